// Round 1
// 526.637 us; speedup vs baseline: 1.1596x; 1.1596x over previous
//
#include <hip/hip_runtime.h>
#include <cstdint>
#include <cmath>

// Problem constants (B,S,D,F,E,K,H = 4,1024,512,2048,8,2,8; HEAD_DIM=64)
#define Bc 4
#define Sc 1024
#define Dc 512
#define Fc 2048
#define Ec 8
#define Hc 8
#define Mc 4096  // B*S

typedef unsigned short u16;
typedef __attribute__((ext_vector_type(8))) short bf16x8;  // 8 bf16 = 4 VGPRs
typedef __attribute__((ext_vector_type(4))) float f32x4;

__device__ __forceinline__ float bf2f(u16 u) {
  unsigned v = ((unsigned)u) << 16;
  return __builtin_bit_cast(float, v);
}
__device__ __forceinline__ u16 f2bf(float f) {
  unsigned u = __builtin_bit_cast(unsigned, f);
  unsigned r = 0x7fffu + ((u >> 16) & 1u);
  return (u16)((u + r) >> 16);
}
__device__ __forceinline__ unsigned pack2bf(float a, float b) {
  return (unsigned)f2bf(a) | ((unsigned)f2bf(b) << 16);
}
// tanh-approx GELU (max abs err ~3e-4 vs exact erf-GELU; threshold headroom is ~0.07)
__device__ __forceinline__ float gelu_f(float x) {
  const float z = 1.5957691216057308f * fmaf(0.044715f * x, x * x, x);  // 2*sqrt(2/pi)*(x+c x^3)
  const float e = __expf(z);
  return x * (1.0f - __builtin_amdgcn_rcpf(e + 1.0f));
}
// async global->LDS, 16B per lane; LDS dest = base + lane*16 (wave-uniform base)
__device__ __forceinline__ void async16(const void* g, void* l) {
  __builtin_amdgcn_global_load_lds(
      (const __attribute__((address_space(1))) unsigned int*)g,
      (__attribute__((address_space(3))) unsigned int*)l, 16, 0, 0);
}

// f32 -> bf16 conversion, 4 elems/thread
__global__ __launch_bounds__(256) void cvt_kernel(const float* __restrict__ in,
                                                  u16* __restrict__ outp, long long n) {
  const long long i = ((long long)blockIdx.x * 256 + threadIdx.x) * 4;
  if (i < n) {
    const float4 v = *(const float4*)(in + i);
    ushort4 o;
    o.x = f2bf(v.x); o.y = f2bf(v.y); o.z = f2bf(v.z); o.w = f2bf(v.w);
    *(ushort4*)(outp + i) = o;
  }
}

// ---------------- gating precompute: weq[e][d] = sum_j eq[e][j] * gWk[j][d] ----------------
__global__ __launch_bounds__(256) void weq_kernel(const float* __restrict__ gWk,
                                                  const float* __restrict__ eq,
                                                  float* __restrict__ weq) {
  __shared__ float red[4][64];
  const int tid = threadIdx.x, wave = tid >> 6, lane = tid & 63;
  const int d = blockIdx.x * 64 + lane;
  const int e = blockIdx.y;
  float acc = 0.f;
  for (int j = wave * 128; j < wave * 128 + 128; ++j)
    acc += gWk[(long long)j * 512 + d] * eq[e * 512 + j];
  red[wave][lane] = acc;
  __syncthreads();
  if (wave == 0)
    weq[e * 512 + d] = red[0][lane] + red[1][lane] + red[2][lane] + red[3][lane];
}
__global__ void beq_kernel(const float* __restrict__ gbk, const float* __restrict__ eq,
                           float* __restrict__ beq) {
  const int wave = threadIdx.x >> 6, lane = threadIdx.x & 63;
  for (int e = wave; e < 8; e += 4) {
    float a = 0.f;
#pragma unroll
    for (int i = 0; i < 8; ++i) a += gbk[lane + 64 * i] * eq[e * 512 + lane + 64 * i];
#pragma unroll
    for (int off = 32; off; off >>= 1) a += __shfl_xor(a, off);
    if (lane == 0) beq[e] = a;
  }
}

// ---- gating: scores = (x@weq^T + beq)*D^-0.5, softmax(E=8), top-2, renorm; build routing lists --
__global__ __launch_bounds__(256) void gate_kernel(const float* __restrict__ x,
                                                   const float* __restrict__ weq,
                                                   const float* __restrict__ beq,
                                                   float* __restrict__ gated,
                                                   int* __restrict__ cnt, int* __restrict__ tlist,
                                                   int* __restrict__ pos) {
  const int wave = threadIdx.x >> 6, lane = threadIdx.x & 63;
  const int t = blockIdx.x * 4 + wave;
  const float* xr = x + (long long)t * 512;
  float acc[8] = {};
#pragma unroll
  for (int i = 0; i < 8; ++i) {
    const float xv = xr[lane + 64 * i];
#pragma unroll
    for (int e2 = 0; e2 < 8; ++e2) acc[e2] += xv * weq[e2 * 512 + lane + 64 * i];
  }
#pragma unroll
  for (int e2 = 0; e2 < 8; ++e2)
#pragma unroll
    for (int off = 32; off; off >>= 1) acc[e2] += __shfl_xor(acc[e2], off);
  if (lane == 0) {
    const float scale = 0.044194173824159216f;  // 512^-0.5
    float s[8], mx = -1e30f;
#pragma unroll
    for (int e2 = 0; e2 < 8; ++e2) { s[e2] = (acc[e2] + beq[e2]) * scale; mx = fmaxf(mx, s[e2]); }
    float p[8], sum = 0.f;
#pragma unroll
    for (int e2 = 0; e2 < 8; ++e2) { p[e2] = expf(s[e2] - mx); sum += p[e2]; }
#pragma unroll
    for (int e2 = 0; e2 < 8; ++e2) p[e2] /= sum;
    int i1 = 0;
#pragma unroll
    for (int e2 = 1; e2 < 8; ++e2) if (p[e2] > p[i1]) i1 = e2;
    int i2 = (i1 == 0) ? 1 : 0;
#pragma unroll
    for (int e2 = 0; e2 < 8; ++e2) if (e2 != i1 && e2 != i2 && p[e2] > p[i2]) i2 = e2;
    const float denom = p[i1] + p[i2] + 1e-9f;
#pragma unroll
    for (int e2 = 0; e2 < 8; ++e2)
      gated[t * 8 + e2] = (e2 == i1 || e2 == i2) ? p[e2] / denom : 0.f;
    const int b = t >> 10;
    int s1 = atomicAdd(cnt + i1 * 4 + b, 1);
    tlist[(i1 * 4 + b) * 1024 + s1] = t;
    pos[i1 * 4096 + t] = s1;
    int s2 = atomicAdd(cnt + i2 * 4 + b, 1);
    tlist[(i2 * 4 + b) * 1024 + s2] = t;
    pos[i2 * 4096 + t] = s2;
  }
}

// pad each (e,b) segment of tlist to a multiple of 128 with a valid token (row 0 of sequence b)
__global__ void pad_kernel(const int* __restrict__ cnt, int* __restrict__ tlist) {
  const int seg = blockIdx.x;
  const int c = cnt[seg];
  const int ce = (c + 127) & ~127;
  const int tpad = (seg & 3) << 10;
  for (int i = c + (int)threadIdx.x; i < ce; i += 128) tlist[seg * 1024 + i] = tpad;
}

// ---- work list: compact (seg,tile) items so active routed-GEMM blocks are CONTIGUOUS in ----
// ---- linear block id (spreads across all 8 XCDs; old bseg*8+tile encoding aliased to   ----
// ---- linear_id mod 8 in {0..2} -> all real work on 2-3 XCDs, occupancy 5.6%).          ----
// total <= 92 (per b: sum_e ceil(cnt/128) <= 2048/128 + 7); wl[96] holds total.
__global__ void wl_kernel(const int* __restrict__ cnt, int* __restrict__ wl) {
  const int seg = threadIdx.x;
  if (seg >= 32) return;
  int base = 0;
  for (int s = 0; s < seg; ++s) base += (cnt[s] + 127) >> 7;
  const int nt = (cnt[seg] + 127) >> 7;
  for (int t = 0; t < nt; ++t) wl[base + t] = (seg << 8) | t;
  if (seg == 31) wl[96] = base + nt;
}

// ---------------- bf16 MFMA GEMM: C[m,n] = sum_k A[m,k]*Bt[n,k] + bias[n] ----------------
// 128x128 tile, BK in {64,128}, 4 waves each 64x64 (4x4 of 16x16x32 MFMA), operand-swapped
// epilogue. ROUTED path reads its (expert, bseg, tile) from the compacted work list wl.
template <int GELU, int QKV, int ROUTED, int BK>
__global__ __launch_bounds__(256) void gemm_bf16(
    const u16* __restrict__ A, const u16* __restrict__ Bw, const float* __restrict__ bias,
    u16* __restrict__ Cout, u16* __restrict__ vT, int M, int N, int K, long long Astride,
    const int* __restrict__ wl) {
  int e;
  long long bm;
  if (ROUTED) {
    const int total = wl[96];
    if ((int)blockIdx.x >= total) return;
    const int item = wl[blockIdx.x];
    const int seg = item >> 8, tile = item & 255;
    e = seg >> 2;
    bm = ((long long)(seg & 3) << 10) + tile * 128;
  } else {
    e = blockIdx.z;
    bm = (long long)blockIdx.x * 128;
  }
  __shared__ __attribute__((aligned(16))) u16 As[128 * BK];
  __shared__ __attribute__((aligned(16))) u16 Bs[128 * BK];
  const int tid = threadIdx.x;
  const int wave = tid >> 6, lane = tid & 63;
  const long long bn = (long long)blockIdx.y * 128;
  const u16* Ag = A + (long long)e * Astride + bm * K;
  const u16* Bg = Bw + ((long long)e * N + bn) * K;
  constexpr int LPR = BK / 8;   // lanes per row in a staging instruction
  constexpr int RPI = 512 / BK; // rows per staging instruction
  constexpr int IPW = BK / 16;  // staging instructions per wave (each of A and B)
  const int lrow = lane / LPR, lpos = lane % LPR;
  const int lm = lane & 15, quad = lane >> 4;
  const int wm = (wave >> 1) * 64, wn = (wave & 1) * 64;
  f32x4 acc[4][4] = {};
  for (int kk = 0; kk < K; kk += BK) {
    __syncthreads();
#pragma unroll
    for (int i = 0; i < IPW; ++i) {
      const int gi = wave * IPW + i;        // instruction slot 0..BK/4-1
      const int row = gi * RPI + lrow;      // tile row 0..127
      const int sc = lpos ^ (row & 7);      // XOR-swizzled source chunk
      async16(Ag + (long long)row * K + kk + sc * 8, &As[gi * 512]);
      async16(Bg + (long long)row * K + kk + sc * 8, &Bs[gi * 512]);
    }
    __syncthreads();
#pragma unroll
    for (int ks = 0; ks < BK / 32; ++ks) {
      bf16x8 af[4], bfr[4];
#pragma unroll
      for (int mi = 0; mi < 4; ++mi) {
        const int row = wm + mi * 16 + lm;
        const int ch = (ks * 4 + quad) ^ (row & 7);
        af[mi] = *(const bf16x8*)(As + row * BK + ch * 8);
      }
#pragma unroll
      for (int nj = 0; nj < 4; ++nj) {
        const int row = wn + nj * 16 + lm;
        const int ch = (ks * 4 + quad) ^ (row & 7);
        bfr[nj] = *(const bf16x8*)(Bs + row * BK + ch * 8);
      }
#pragma unroll
      for (int mi = 0; mi < 4; ++mi)
#pragma unroll
        for (int nj = 0; nj < 4; ++nj)
          acc[mi][nj] = __builtin_amdgcn_mfma_f32_16x16x32_bf16(bfr[nj], af[mi], acc[mi][nj], 0, 0, 0);
    }
  }
  // Epilogue: lane owns row m = bm+wm+mi*16+lm, 4 consecutive cols n0 = bn+wn+nj*16+quad*4
  const float* bs = bias + (long long)e * N;
#pragma unroll
  for (int mi = 0; mi < 4; ++mi) {
    const int m = (int)bm + wm + mi * 16 + lm;
#pragma unroll
    for (int nj = 0; nj < 4; ++nj) {
      const int n0 = (int)bn + wn + nj * 16 + quad * 4;
      const float4 bv = *(const float4*)(bs + n0);
      float v0 = acc[mi][nj][0] + bv.x;
      float v1 = acc[mi][nj][1] + bv.y;
      float v2 = acc[mi][nj][2] + bv.z;
      float v3 = acc[mi][nj][3] + bv.w;
      if (GELU) { v0 = gelu_f(v0); v1 = gelu_f(v1); v2 = gelu_f(v2); v3 = gelu_f(v3); }
      if (QKV) {
        if (n0 < 1024) {  // q,k packed [e][t][1024] (branch uniform per block-y)
          uint2 pk; pk.x = pack2bf(v0, v1); pk.y = pack2bf(v2, v3);
          *(uint2*)(Cout + ((long long)e * Mc + m) * 1024 + n0) = pk;
        } else {  // v stored transposed [e][b][h][64][S]; 4 consecutive d -> 4 rows
          const int hh = (n0 - 1024) >> 6, dd = (n0 - 1024) & 63;
          const int bb = m >> 10, ss = m & 1023;
          u16* vp = vT + ((((long long)e * Bc + bb) * Hc + hh) * 64 + dd) * Sc + ss;
          vp[0] = f2bf(v0); vp[Sc] = f2bf(v1); vp[2 * Sc] = f2bf(v2); vp[3 * Sc] = f2bf(v3);
        }
      } else {
        uint2 pk; pk.x = pack2bf(v0, v1); pk.y = pack2bf(v2, v3);
        *(uint2*)(Cout + ((long long)e * M + m) * N + n0) = pk;
      }
    }
  }
}

// -------- flash attention: ONE block per (e,b,h); processes ALL its routed q-tiles --------
// K/V chunk staged once per n0 round and reused by up to 4 q-tiles (register-resident aq/O/ap),
// amortizing both staging rounds and global_load_lds instructions ~4x vs one-block-per-q-tile.
__global__ __launch_bounds__(256, 1) void attn_fused(const u16* __restrict__ qk,
                                                     const u16* __restrict__ vT,
                                                     u16* __restrict__ ctx,
                                                     const int* __restrict__ cnt,
                                                     const int* __restrict__ tlist) {
  const int bh = blockIdx.x;
  const int b = bh >> 3, h = bh & 7;
  const int e = blockIdx.y;
  const int seg = (e << 2) + b;
  const int ce = (cnt[seg] + 127) & ~127;  // padded row count (tlist defined up to ce)
  const int T = ce >> 6;                   // q-tiles to compute (covers all GEMM-visible rows)
  if (T == 0) return;
  __shared__ __attribute__((aligned(16))) u16 Ks[64 * 64];     // [key][d] swizzled
  __shared__ __attribute__((aligned(16))) u16 Vs[64 * 64];     // [d][key] swizzled
  __shared__ __attribute__((aligned(16))) u16 Pl[4][16 * 72];  // per-wave P[q][key], stride 72
  const int tid = threadIdx.x, wave = tid >> 6, lane = tid & 63;
  const int lm = lane & 15, quad = lane >> 4;
  const u16* qkbase = qk + (long long)e * Mc * 1024;
  const u16* vbase = vT + ((((long long)e * Bc + b) * Hc + h) * 64) * Sc;
  const int lr = lane >> 3, lc = (lane & 7) ^ lr;
  u16* P = &Pl[wave][0];
  unsigned* P32 = (unsigned*)P;
  const int pwbase = lm * 36 + quad * 2;  // dword index of this lane's P writes

  for (int qg = 0; qg < T; qg += 4) {
    const int tcnt = (T - qg < 4) ? (T - qg) : 4;  // block-uniform
    bf16x8 aq[4][2];
    f32x4 O[4][4] = {};
    float lsum[4] = {0.f, 0.f, 0.f, 0.f};
#pragma unroll
    for (int t = 0; t < 4; ++t)
      if (t < tcnt) {
        const int pidx = seg * 1024 + (qg + t) * 64 + wave * 16 + lm;
        const int tq = tlist[pidx];
#pragma unroll
        for (int ks = 0; ks < 2; ++ks)
          aq[t][ks] = *(const bf16x8*)(qkbase + (long long)tq * 1024 + h * 64 + ks * 32 + quad * 8);
      }
    for (int n0 = 0; n0 < Sc; n0 += 64) {
      __syncthreads();
#pragma unroll
      for (int i = 0; i < 2; ++i) {
        const int rg = wave * 2 + i;  // 0..7
        const int row = rg * 8 + lr;  // 0..63
        async16(qkbase + ((long long)b * Sc + n0 + row) * 1024 + 512 + h * 64 + lc * 8,
                &Ks[rg * 512]);
        async16(vbase + (long long)row * Sc + n0 + lc * 8, &Vs[rg * 512]);
      }
      __syncthreads();
      // hoist K fragments (t-invariant)
      bf16x8 kf[4][2];
#pragma unroll
      for (int kj = 0; kj < 4; ++kj) {
        const int row = kj * 16 + lm;
        kf[kj][0] = *(const bf16x8*)(Ks + row * 64 + ((quad) ^ (row & 7)) * 8);
        kf[kj][1] = *(const bf16x8*)(Ks + row * 64 + ((4 + quad) ^ (row & 7)) * 8);
      }
      bf16x8 ap[4][2];
#pragma unroll
      for (int t = 0; t < 4; ++t)
        if (t < tcnt) {
          // S^T = K @ Q^T : C-layout row = key = kj*16 + quad*4 + r, col = q = lm
          f32x4 sT[4];
#pragma unroll
          for (int kj = 0; kj < 4; ++kj) {
            f32x4 c = {};
            c = __builtin_amdgcn_mfma_f32_16x16x32_bf16(kf[kj][0], aq[t][0], c, 0, 0, 0);
            c = __builtin_amdgcn_mfma_f32_16x16x32_bf16(kf[kj][1], aq[t][1], c, 0, 0, 0);
            sT[kj] = c;
          }
          // p = exp(s/8) (scores bounded -> no running-max rescale); local denom
#pragma unroll
          for (int kj = 0; kj < 4; ++kj) {
            const float p0 = __expf(sT[kj][0] * 0.125f);
            const float p1 = __expf(sT[kj][1] * 0.125f);
            const float p2 = __expf(sT[kj][2] * 0.125f);
            const float p3 = __expf(sT[kj][3] * 0.125f);
            lsum[t] += (p0 + p1) + (p2 + p3);
            P32[pwbase + kj * 8 + 0] = pack2bf(p0, p1);
            P32[pwbase + kj * 8 + 1] = pack2bf(p2, p3);
          }
          asm volatile("s_waitcnt lgkmcnt(0)" ::: "memory");
          ap[t][0] = *(const bf16x8*)(P + lm * 72 + quad * 8);
          ap[t][1] = *(const bf16x8*)(P + lm * 72 + 32 + quad * 8);
        }
      // PV with hoisted V fragments: O^T[d][q] += V^T[d][key] * P[q][key]
#pragma unroll
      for (int d4 = 0; d4 < 4; ++d4) {
        const int row = d4 * 16 + lm;
        bf16x8 v0 = *(const bf16x8*)(Vs + row * 64 + ((quad) ^ (row & 7)) * 8);
        bf16x8 v1 = *(const bf16x8*)(Vs + row * 64 + ((4 + quad) ^ (row & 7)) * 8);
#pragma unroll
        for (int t = 0; t < 4; ++t)
          if (t < tcnt) {
            O[t][d4] = __builtin_amdgcn_mfma_f32_16x16x32_bf16(v0, ap[t][0], O[t][d4], 0, 0, 0);
            O[t][d4] = __builtin_amdgcn_mfma_f32_16x16x32_bf16(v1, ap[t][1], O[t][d4], 0, 0, 0);
          }
      }
    }
#pragma unroll
    for (int t = 0; t < 4; ++t)
      if (t < tcnt) {
        float ls = lsum[t];
        ls += __shfl_xor(ls, 16);
        ls += __shfl_xor(ls, 32);
        const float inv = 1.0f / ls;  // per-lane correct for q = lm
        const long long pidx = seg * 1024 + (qg + t) * 64 + wave * 16 + lm;
#pragma unroll
        for (int d4 = 0; d4 < 4; ++d4) {
          uint2 pk;
          pk.x = pack2bf(O[t][d4][0] * inv, O[t][d4][1] * inv);
          pk.y = pack2bf(O[t][d4][2] * inv, O[t][d4][3] * inv);
          *(uint2*)(ctx + pidx * 512 + h * 64 + d4 * 16 + quad * 4) = pk;
        }
      }
  }
}

// ---------------- LN1 (routed): x1[p] = LN(x[tlist[p]] + ctxp[p]; g1,be1) -> bf16 ----------------
__global__ __launch_bounds__(256) void ln1_kernel(const float* __restrict__ x,
                                                  const u16* __restrict__ ctxp,
                                                  const float* __restrict__ g1,
                                                  const float* __restrict__ be1,
                                                  u16* __restrict__ x1,
                                                  const int* __restrict__ cnt,
                                                  const int* __restrict__ tlist) {
  const int i = blockIdx.x, b = blockIdx.y, e = blockIdx.z;
  const int seg = (e << 2) + b;
  const int ce = (cnt[seg] + 127) & ~127;
  if (i >= ce) return;  // compute all padded rows so downstream GEMM reads defined data
  const long long p = seg * 1024 + i;
  const int t = tlist[p];
  const int tid = threadIdx.x;
  const int wave = tid >> 6, lane = tid & 63;
  __shared__ float sred[4], qred[4];
  const float v0 = x[(long long)t * 512 + tid] + bf2f(ctxp[p * 512 + tid]);
  const float v1 = x[(long long)t * 512 + tid + 256] + bf2f(ctxp[p * 512 + tid + 256]);
  float s = v0 + v1, q = v0 * v0 + v1 * v1;
#pragma unroll
  for (int off = 32; off; off >>= 1) { s += __shfl_xor(s, off); q += __shfl_xor(q, off); }
  if (lane == 0) { sred[wave] = s; qred[wave] = q; }
  __syncthreads();
  s = sred[0] + sred[1] + sred[2] + sred[3];
  q = qred[0] + qred[1] + qred[2] + qred[3];
  const float mean = s * (1.0f / 512.0f);
  const float var = q * (1.0f / 512.0f) - mean * mean;
  const float rstd = rsqrtf(var + 1e-5f);
  x1[p * 512 + tid] = f2bf((v0 - mean) * rstd * g1[e * 512 + tid] + be1[e * 512 + tid]);
  x1[p * 512 + tid + 256] =
      f2bf((v1 - mean) * rstd * g1[e * 512 + tid + 256] + be1[e * 512 + tid + 256]);
}

// ---------------- LN2 + gate-weighted combine: out[t] = sum_e w[t,e]*LN(x1[p]+h2[p]) ----------------
__global__ __launch_bounds__(256) void ln2_kernel(const u16* __restrict__ x1,
                                                  const u16* __restrict__ h2,
                                                  const float* __restrict__ g2,
                                                  const float* __restrict__ be2,
                                                  const float* __restrict__ gated,
                                                  const int* __restrict__ pos,
                                                  float* __restrict__ out) {
  const int t = blockIdx.x, tid = threadIdx.x;
  const int b = t >> 10;
  const int wave = tid >> 6, lane = tid & 63;
  __shared__ float sred[4], qred[4];
  float o0 = 0.f, o1 = 0.f;
  for (int e = 0; e < 8; ++e) {
    const float wgt = gated[t * 8 + e];
    if (wgt != 0.f) {  // block-uniform branch (depends on t only)
      const long long p = ((e << 2) + b) * 1024 + pos[e * 4096 + t];
      const float v0 = bf2f(x1[p * 512 + tid]) + bf2f(h2[p * 512 + tid]);
      const float v1 = bf2f(x1[p * 512 + tid + 256]) + bf2f(h2[p * 512 + tid + 256]);
      float s = v0 + v1, q = v0 * v0 + v1 * v1;
#pragma unroll
      for (int off = 32; off; off >>= 1) { s += __shfl_xor(s, off); q += __shfl_xor(q, off); }
      if (lane == 0) { sred[wave] = s; qred[wave] = q; }
      __syncthreads();
      s = sred[0] + sred[1] + sred[2] + sred[3];
      q = qred[0] + qred[1] + qred[2] + qred[3];
      __syncthreads();
      const float mean = s * (1.0f / 512.0f);
      const float var = q * (1.0f / 512.0f) - mean * mean;
      const float rstd = rsqrtf(var + 1e-5f);
      o0 += wgt * ((v0 - mean) * rstd * g2[e * 512 + tid] + be2[e * 512 + tid]);
      o1 += wgt * ((v1 - mean) * rstd * g2[e * 512 + tid + 256] + be2[e * 512 + tid + 256]);
    }
  }
  out[(long long)t * 512 + tid] = o0;
  out[(long long)t * 512 + tid + 256] = o1;
}

// ---------------- launch ----------------
extern "C" void kernel_launch(void* const* d_in, const int* in_sizes, int n_in, void* d_out,
                              int out_size, void* d_ws, size_t ws_size, hipStream_t stream) {
  const float* x    = (const float*)d_in[0];
  const float* gWk  = (const float*)d_in[1];
  const float* gbk  = (const float*)d_in[2];
  const float* eq   = (const float*)d_in[3];
  const float* Wqkv = (const float*)d_in[4];
  const float* bqkv = (const float*)d_in[5];
  const float* Wo   = (const float*)d_in[6];
  const float* bo   = (const float*)d_in[7];
  const float* g1   = (const float*)d_in[8];
  const float* be1  = (const float*)d_in[9];
  const float* W1   = (const float*)d_in[10];
  const float* bf1  = (const float*)d_in[11];
  const float* W2   = (const float*)d_in[12];
  const float* bf2  = (const float*)d_in[13];
  const float* g2   = (const float*)d_in[14];
  const float* be2  = (const float*)d_in[15];
  float* out = (float*)d_out;

  char* wsp = (char*)d_ws;
  size_t off = 0;
  auto take = [&](size_t bytes) -> void* {
    void* p = wsp + off;
    off += (bytes + 255) & ~(size_t)255;
    return p;
  };
  u16* xb    = (u16*)take((size_t)Mc * 512 * 2);
  u16* Wqkvb = (u16*)take((size_t)Ec * 1536 * 512 * 2);
  u16* Wob   = (u16*)take((size_t)Ec * 512 * 512 * 2);
  u16* W1b   = (u16*)take((size_t)Ec * 2048 * 512 * 2);
  u16* W2b   = (u16*)take((size_t)Ec * 512 * 2048 * 2);
  float* weq   = (float*)take(8 * 512 * 4);
  float* beqb  = (float*)take(8 * 4);
  float* gated = (float*)take((size_t)Mc * 8 * 4);
  int* cnt   = (int*)take(32 * 4);
  int* tlist = (int*)take(32 * 1024 * 4);
  int* pos   = (int*)take((size_t)Ec * Mc * 4);
  int* wl    = (int*)take(128 * 4);
  char* big = (char*)take(134217728);
  u16* qkb  = (u16*)big;                  // [E][M][1024], dead after attn
  u16* vTb  = (u16*)(big + 67108864);     // [E][B][H][64][S], dead after attn
  u16* ctxp = (u16*)(big + 100663296);    // compact [32768][512], dead after ln1
  u16* hb   = (u16*)big;                  // compact [32768][2048], written after ln1
  u16* ctxb = (u16*)take(33554432);       // compact attn out, dead after Wo GEMM
  u16* h2b  = ctxb;                       // compact W2 out, written after W1
  u16* x1b  = (u16*)take(33554432);       // compact [32768][512]
  (void)in_sizes; (void)n_in; (void)out_size; (void)ws_size;

  // fp32 -> bf16 converts
  cvt_kernel<<<dim3(2048), dim3(256), 0, stream>>>(x, xb, (long long)Mc * 512);
  cvt_kernel<<<dim3(6144), dim3(256), 0, stream>>>(Wqkv, Wqkvb, (long long)Ec * 1536 * 512);
  cvt_kernel<<<dim3(2048), dim3(256), 0, stream>>>(Wo, Wob, (long long)Ec * 512 * 512);
  cvt_kernel<<<dim3(8192), dim3(256), 0, stream>>>(W1, W1b, (long long)Ec * 2048 * 512);
  cvt_kernel<<<dim3(8192), dim3(256), 0, stream>>>(W2, W2b, (long long)Ec * 512 * 2048);
  // gating (fp32 path; keys GEMM folded into weq precompute)
  hipMemsetAsync(cnt, 0, 32 * 4, stream);
  weq_kernel<<<dim3(8, 8), dim3(256), 0, stream>>>(gWk, eq, weq);
  beq_kernel<<<dim3(1), dim3(256), 0, stream>>>(gbk, eq, beqb);
  gate_kernel<<<dim3(1024), dim3(256), 0, stream>>>(x, weq, beqb, gated, cnt, tlist, pos);
  pad_kernel<<<dim3(32), dim3(128), 0, stream>>>(cnt, tlist);
  wl_kernel<<<dim3(1), dim3(64), 0, stream>>>(cnt, wl);
  // qkv dense (k,v needed at all tokens) — BK=64
  gemm_bf16<0, 1, 0, 64><<<dim3(32, 12, 8), dim3(256), 0, stream>>>(xb, Wqkvb, bqkv, qkb, vTb, Mc, 1536, 512, 0LL, wl);
  // routed expert pipeline — BK=128, work-list-compacted grids (active blocks contiguous)
  attn_fused<<<dim3(32, 8), dim3(256), 0, stream>>>(qkb, vTb, ctxb, cnt, tlist);
  gemm_bf16<0, 0, 1, 128><<<dim3(96, 4), dim3(256), 0, stream>>>(ctxb, Wob, bo, ctxp, nullptr, Mc, 512, 512, (long long)Mc * 512, wl);
  ln1_kernel<<<dim3(1024, 4, 8), dim3(256), 0, stream>>>(x, ctxp, g1, be1, x1b, cnt, tlist);
  gemm_bf16<1, 0, 1, 128><<<dim3(96, 16), dim3(256), 0, stream>>>(x1b, W1b, bf1, hb, nullptr, Mc, 2048, 512, (long long)Mc * 512, wl);
  gemm_bf16<1, 0, 1, 128><<<dim3(96, 4), dim3(256), 0, stream>>>(hb, W2b, bf2, h2b, nullptr, Mc, 512, 2048, (long long)Mc * 2048, wl);
  ln2_kernel<<<dim3(4096), dim3(256), 0, stream>>>(x1b, h2b, g2, be2, gated, pos, out);
}

// Round 2
// 509.747 us; speedup vs baseline: 1.1980x; 1.0331x over previous
//
#include <hip/hip_runtime.h>
#include <cstdint>
#include <cmath>

// Problem constants (B,S,D,F,E,K,H = 4,1024,512,2048,8,2,8; HEAD_DIM=64)
#define Bc 4
#define Sc 1024
#define Dc 512
#define Fc 2048
#define Ec 8
#define Hc 8
#define Mc 4096  // B*S

typedef unsigned short u16;
typedef __attribute__((ext_vector_type(8))) short bf16x8;  // 8 bf16 = 4 VGPRs
typedef __attribute__((ext_vector_type(4))) float f32x4;

__device__ __forceinline__ float bf2f(u16 u) {
  unsigned v = ((unsigned)u) << 16;
  return __builtin_bit_cast(float, v);
}
__device__ __forceinline__ u16 f2bf(float f) {
  unsigned u = __builtin_bit_cast(unsigned, f);
  unsigned r = 0x7fffu + ((u >> 16) & 1u);
  return (u16)((u + r) >> 16);
}
__device__ __forceinline__ unsigned pack2bf(float a, float b) {
  return (unsigned)f2bf(a) | ((unsigned)f2bf(b) << 16);
}
// tanh-approx GELU (max abs err ~3e-4 vs exact erf-GELU; threshold headroom is ~0.07)
__device__ __forceinline__ float gelu_f(float x) {
  const float z = 1.5957691216057308f * fmaf(0.044715f * x, x * x, x);  // 2*sqrt(2/pi)*(x+c x^3)
  const float e = __expf(z);
  return x * (1.0f - __builtin_amdgcn_rcpf(e + 1.0f));
}
// async global->LDS, 16B per lane; LDS dest = base + lane*16 (wave-uniform base)
__device__ __forceinline__ void async16(const void* g, void* l) {
  __builtin_amdgcn_global_load_lds(
      (const __attribute__((address_space(1))) unsigned int*)g,
      (__attribute__((address_space(3))) unsigned int*)l, 16, 0, 0);
}

// f32 -> bf16 conversion, 4 elems/thread
__global__ __launch_bounds__(256) void cvt_kernel(const float* __restrict__ in,
                                                  u16* __restrict__ outp, long long n) {
  const long long i = ((long long)blockIdx.x * 256 + threadIdx.x) * 4;
  if (i < n) {
    const float4 v = *(const float4*)(in + i);
    ushort4 o;
    o.x = f2bf(v.x); o.y = f2bf(v.y); o.z = f2bf(v.z); o.w = f2bf(v.w);
    *(ushort4*)(outp + i) = o;
  }
}

// ---------------- gating precompute: weq[e][d] = sum_j eq[e][j] * gWk[j][d] ----------------
__global__ __launch_bounds__(256) void weq_kernel(const float* __restrict__ gWk,
                                                  const float* __restrict__ eq,
                                                  float* __restrict__ weq) {
  __shared__ float red[4][64];
  const int tid = threadIdx.x, wave = tid >> 6, lane = tid & 63;
  const int d = blockIdx.x * 64 + lane;
  const int e = blockIdx.y;
  float acc = 0.f;
  for (int j = wave * 128; j < wave * 128 + 128; ++j)
    acc += gWk[(long long)j * 512 + d] * eq[e * 512 + j];
  red[wave][lane] = acc;
  __syncthreads();
  if (wave == 0)
    weq[e * 512 + d] = red[0][lane] + red[1][lane] + red[2][lane] + red[3][lane];
}
__global__ void beq_kernel(const float* __restrict__ gbk, const float* __restrict__ eq,
                           float* __restrict__ beq) {
  const int wave = threadIdx.x >> 6, lane = threadIdx.x & 63;
  for (int e = wave; e < 8; e += 4) {
    float a = 0.f;
#pragma unroll
    for (int i = 0; i < 8; ++i) a += gbk[lane + 64 * i] * eq[e * 512 + lane + 64 * i];
#pragma unroll
    for (int off = 32; off; off >>= 1) a += __shfl_xor(a, off);
    if (lane == 0) beq[e] = a;
  }
}

// ---- gating: scores = (x@weq^T + beq)*D^-0.5, softmax(E=8), top-2, renorm; build routing lists --
__global__ __launch_bounds__(256) void gate_kernel(const float* __restrict__ x,
                                                   const float* __restrict__ weq,
                                                   const float* __restrict__ beq,
                                                   float* __restrict__ gated,
                                                   int* __restrict__ cnt, int* __restrict__ tlist,
                                                   int* __restrict__ pos) {
  const int wave = threadIdx.x >> 6, lane = threadIdx.x & 63;
  const int t = blockIdx.x * 4 + wave;
  const float* xr = x + (long long)t * 512;
  float acc[8] = {};
#pragma unroll
  for (int i = 0; i < 8; ++i) {
    const float xv = xr[lane + 64 * i];
#pragma unroll
    for (int e2 = 0; e2 < 8; ++e2) acc[e2] += xv * weq[e2 * 512 + lane + 64 * i];
  }
#pragma unroll
  for (int e2 = 0; e2 < 8; ++e2)
#pragma unroll
    for (int off = 32; off; off >>= 1) acc[e2] += __shfl_xor(acc[e2], off);
  if (lane == 0) {
    const float scale = 0.044194173824159216f;  // 512^-0.5
    float s[8], mx = -1e30f;
#pragma unroll
    for (int e2 = 0; e2 < 8; ++e2) { s[e2] = (acc[e2] + beq[e2]) * scale; mx = fmaxf(mx, s[e2]); }
    float p[8], sum = 0.f;
#pragma unroll
    for (int e2 = 0; e2 < 8; ++e2) { p[e2] = expf(s[e2] - mx); sum += p[e2]; }
#pragma unroll
    for (int e2 = 0; e2 < 8; ++e2) p[e2] /= sum;
    int i1 = 0;
#pragma unroll
    for (int e2 = 1; e2 < 8; ++e2) if (p[e2] > p[i1]) i1 = e2;
    int i2 = (i1 == 0) ? 1 : 0;
#pragma unroll
    for (int e2 = 0; e2 < 8; ++e2) if (e2 != i1 && e2 != i2 && p[e2] > p[i2]) i2 = e2;
    const float denom = p[i1] + p[i2] + 1e-9f;
#pragma unroll
    for (int e2 = 0; e2 < 8; ++e2)
      gated[t * 8 + e2] = (e2 == i1 || e2 == i2) ? p[e2] / denom : 0.f;
    const int b = t >> 10;
    int s1 = atomicAdd(cnt + i1 * 4 + b, 1);
    tlist[(i1 * 4 + b) * 1024 + s1] = t;
    pos[i1 * 4096 + t] = s1;
    int s2 = atomicAdd(cnt + i2 * 4 + b, 1);
    tlist[(i2 * 4 + b) * 1024 + s2] = t;
    pos[i2 * 4096 + t] = s2;
  }
}

// pad each (e,b) segment of tlist to a multiple of 128 with a valid token (row 0 of sequence b)
__global__ void pad_kernel(const int* __restrict__ cnt, int* __restrict__ tlist) {
  const int seg = blockIdx.x;
  const int c = cnt[seg];
  const int ce = (c + 127) & ~127;
  const int tpad = (seg & 3) << 10;
  for (int i = c + (int)threadIdx.x; i < ce; i += 128) tlist[seg * 1024 + i] = tpad;
}

// ---- work lists: compact (seg,tile) items so active blocks are CONTIGUOUS in linear ----
// ---- block id (spreads across all 8 XCDs). wl[0..95]: 128-row GEMM tiles, total at  ----
// ---- wl[96]. wl[128..319]: 64-row attn q-tiles, total at wl[97].                    ----
__global__ void wl_kernel(const int* __restrict__ cnt, int* __restrict__ wl) {
  const int seg = threadIdx.x;
  if (seg >= 32) return;
  int base = 0;
  for (int s = 0; s < seg; ++s) base += (cnt[s] + 127) >> 7;
  const int nt = (cnt[seg] + 127) >> 7;
  for (int t = 0; t < nt; ++t) wl[base + t] = (seg << 8) | t;
  for (int t = 0; t < 2 * nt; ++t) wl[128 + 2 * base + t] = (seg << 8) | t;
  if (seg == 31) { wl[96] = base + nt; wl[97] = 2 * (base + nt); }
}

// ---------------- bf16 MFMA GEMM: C[m,n] = sum_k A[m,k]*Bt[n,k] + bias[n] ----------------
// 128x128 tile, BK in {64,128}, 4 waves each 64x64 (4x4 of 16x16x32 MFMA), operand-swapped
// epilogue. ROUTED path reads its (expert, bseg, tile) from the compacted work list wl.
template <int GELU, int QKV, int ROUTED, int BK>
__global__ __launch_bounds__(256) void gemm_bf16(
    const u16* __restrict__ A, const u16* __restrict__ Bw, const float* __restrict__ bias,
    u16* __restrict__ Cout, u16* __restrict__ vT, int M, int N, int K, long long Astride,
    const int* __restrict__ wl) {
  int e;
  long long bm;
  if (ROUTED) {
    const int total = wl[96];
    if ((int)blockIdx.x >= total) return;
    const int item = wl[blockIdx.x];
    const int seg = item >> 8, tile = item & 255;
    e = seg >> 2;
    bm = ((long long)(seg & 3) << 10) + tile * 128;
  } else {
    e = blockIdx.z;
    bm = (long long)blockIdx.x * 128;
  }
  __shared__ __attribute__((aligned(16))) u16 As[128 * BK];
  __shared__ __attribute__((aligned(16))) u16 Bs[128 * BK];
  const int tid = threadIdx.x;
  const int wave = tid >> 6, lane = tid & 63;
  const long long bn = (long long)blockIdx.y * 128;
  const u16* Ag = A + (long long)e * Astride + bm * K;
  const u16* Bg = Bw + ((long long)e * N + bn) * K;
  constexpr int LPR = BK / 8;   // lanes per row in a staging instruction
  constexpr int RPI = 512 / BK; // rows per staging instruction
  constexpr int IPW = BK / 16;  // staging instructions per wave (each of A and B)
  const int lrow = lane / LPR, lpos = lane % LPR;
  const int lm = lane & 15, quad = lane >> 4;
  const int wm = (wave >> 1) * 64, wn = (wave & 1) * 64;
  f32x4 acc[4][4] = {};
  for (int kk = 0; kk < K; kk += BK) {
    __syncthreads();
#pragma unroll
    for (int i = 0; i < IPW; ++i) {
      const int gi = wave * IPW + i;        // instruction slot 0..BK/4-1
      const int row = gi * RPI + lrow;      // tile row 0..127
      const int sc = lpos ^ (row & 7);      // XOR-swizzled source chunk
      async16(Ag + (long long)row * K + kk + sc * 8, &As[gi * 512]);
      async16(Bg + (long long)row * K + kk + sc * 8, &Bs[gi * 512]);
    }
    __syncthreads();
#pragma unroll
    for (int ks = 0; ks < BK / 32; ++ks) {
      bf16x8 af[4], bfr[4];
#pragma unroll
      for (int mi = 0; mi < 4; ++mi) {
        const int row = wm + mi * 16 + lm;
        const int ch = (ks * 4 + quad) ^ (row & 7);
        af[mi] = *(const bf16x8*)(As + row * BK + ch * 8);
      }
#pragma unroll
      for (int nj = 0; nj < 4; ++nj) {
        const int row = wn + nj * 16 + lm;
        const int ch = (ks * 4 + quad) ^ (row & 7);
        bfr[nj] = *(const bf16x8*)(Bs + row * BK + ch * 8);
      }
#pragma unroll
      for (int mi = 0; mi < 4; ++mi)
#pragma unroll
        for (int nj = 0; nj < 4; ++nj)
          acc[mi][nj] = __builtin_amdgcn_mfma_f32_16x16x32_bf16(bfr[nj], af[mi], acc[mi][nj], 0, 0, 0);
    }
  }
  // Epilogue: lane owns row m = bm+wm+mi*16+lm, 4 consecutive cols n0 = bn+wn+nj*16+quad*4
  const float* bs = bias + (long long)e * N;
#pragma unroll
  for (int mi = 0; mi < 4; ++mi) {
    const int m = (int)bm + wm + mi * 16 + lm;
#pragma unroll
    for (int nj = 0; nj < 4; ++nj) {
      const int n0 = (int)bn + wn + nj * 16 + quad * 4;
      const float4 bv = *(const float4*)(bs + n0);
      float v0 = acc[mi][nj][0] + bv.x;
      float v1 = acc[mi][nj][1] + bv.y;
      float v2 = acc[mi][nj][2] + bv.z;
      float v3 = acc[mi][nj][3] + bv.w;
      if (GELU) { v0 = gelu_f(v0); v1 = gelu_f(v1); v2 = gelu_f(v2); v3 = gelu_f(v3); }
      if (QKV) {
        if (n0 < 1024) {  // q,k packed [e][t][1024] (branch uniform per block-y)
          uint2 pk; pk.x = pack2bf(v0, v1); pk.y = pack2bf(v2, v3);
          *(uint2*)(Cout + ((long long)e * Mc + m) * 1024 + n0) = pk;
        } else {  // v stored transposed [e][b][h][64][S]; 4 consecutive d -> 4 rows
          const int hh = (n0 - 1024) >> 6, dd = (n0 - 1024) & 63;
          const int bb = m >> 10, ss = m & 1023;
          u16* vp = vT + ((((long long)e * Bc + bb) * Hc + hh) * 64 + dd) * Sc + ss;
          vp[0] = f2bf(v0); vp[Sc] = f2bf(v1); vp[2 * Sc] = f2bf(v2); vp[3 * Sc] = f2bf(v3);
        }
      } else {
        uint2 pk; pk.x = pack2bf(v0, v1); pk.y = pack2bf(v2, v3);
        *(uint2*)(Cout + ((long long)e * M + m) * N + n0) = pk;
      }
    }
  }
}

// -------- flash attention: ONE block per (q-tile, head) from the q worklist. --------
// 64 q rows per block, K/V chunks staged per 64-key round (L2-resident re-reads across
// blocks). ~1150 active blocks -> ~4.5 blocks/CU, vs 1 block/CU in the fused variant
// (which measured Occupancy 8.5%, MfmaUtil 9.6% -- pure latency-bound starvation).
__global__ __launch_bounds__(256, 4) void attn_tile(const u16* __restrict__ qk,
                                                    const u16* __restrict__ vT,
                                                    u16* __restrict__ ctx,
                                                    const int* __restrict__ wl,
                                                    const int* __restrict__ tlist) {
  if ((int)blockIdx.x >= wl[97]) return;
  const int item = wl[128 + blockIdx.x];
  const int seg = item >> 8, qt = item & 255;
  const int e = seg >> 2, b = seg & 3, h = blockIdx.y;
  __shared__ __attribute__((aligned(16))) u16 Ks[64 * 64];     // [key][d] swizzled
  __shared__ __attribute__((aligned(16))) u16 Vs[64 * 64];     // [d][key] swizzled
  __shared__ __attribute__((aligned(16))) u16 Pl[4][16 * 72];  // per-wave P[q][key], stride 72
  const int tid = threadIdx.x, wave = tid >> 6, lane = tid & 63;
  const int lm = lane & 15, quad = lane >> 4;
  const u16* qkbase = qk + (long long)e * Mc * 1024;
  const u16* vbase = vT + ((((long long)e * Bc + b) * Hc + h) * 64) * Sc;
  const int lr = lane >> 3, lc = (lane & 7) ^ lr;
  u16* P = &Pl[wave][0];
  unsigned* P32 = (unsigned*)P;
  const int pwbase = lm * 36 + quad * 2;  // dword index of this lane's P writes

  // q fragments for this lane's 16 rows (row = qt*64 + wave*16 + lm)
  const long long pidx = (long long)seg * 1024 + qt * 64 + wave * 16 + lm;
  const int tq = tlist[pidx];
  bf16x8 aq[2];
#pragma unroll
  for (int ks = 0; ks < 2; ++ks)
    aq[ks] = *(const bf16x8*)(qkbase + (long long)tq * 1024 + h * 64 + ks * 32 + quad * 8);
  f32x4 O[4] = {};
  float lsum = 0.f;

  for (int n0 = 0; n0 < Sc; n0 += 64) {
    __syncthreads();
#pragma unroll
    for (int i = 0; i < 2; ++i) {
      const int rg = wave * 2 + i;  // 0..7
      const int row = rg * 8 + lr;  // 0..63
      async16(qkbase + ((long long)b * Sc + n0 + row) * 1024 + 512 + h * 64 + lc * 8,
              &Ks[rg * 512]);
      async16(vbase + (long long)row * Sc + n0 + lc * 8, &Vs[rg * 512]);
    }
    __syncthreads();
    // S^T = K @ Q^T : C-layout row = key = kj*16 + quad*4 + r, col = q = lm
    f32x4 sT[4];
#pragma unroll
    for (int kj = 0; kj < 4; ++kj) {
      const int row = kj * 16 + lm;
      const bf16x8 k0 = *(const bf16x8*)(Ks + row * 64 + ((quad) ^ (row & 7)) * 8);
      const bf16x8 k1 = *(const bf16x8*)(Ks + row * 64 + ((4 + quad) ^ (row & 7)) * 8);
      f32x4 c = {};
      c = __builtin_amdgcn_mfma_f32_16x16x32_bf16(k0, aq[0], c, 0, 0, 0);
      c = __builtin_amdgcn_mfma_f32_16x16x32_bf16(k1, aq[1], c, 0, 0, 0);
      sT[kj] = c;
    }
    // p = exp(s/8) (scores bounded -> no running-max rescale); local denom
#pragma unroll
    for (int kj = 0; kj < 4; ++kj) {
      const float p0 = __expf(sT[kj][0] * 0.125f);
      const float p1 = __expf(sT[kj][1] * 0.125f);
      const float p2 = __expf(sT[kj][2] * 0.125f);
      const float p3 = __expf(sT[kj][3] * 0.125f);
      lsum += (p0 + p1) + (p2 + p3);
      P32[pwbase + kj * 8 + 0] = pack2bf(p0, p1);
      P32[pwbase + kj * 8 + 1] = pack2bf(p2, p3);
    }
    asm volatile("s_waitcnt lgkmcnt(0)" ::: "memory");
    const bf16x8 ap0 = *(const bf16x8*)(P + lm * 72 + quad * 8);
    const bf16x8 ap1 = *(const bf16x8*)(P + lm * 72 + 32 + quad * 8);
    // PV: O^T[d][q] += V^T[d][key] * P[q][key]
#pragma unroll
    for (int d4 = 0; d4 < 4; ++d4) {
      const int row = d4 * 16 + lm;
      const bf16x8 v0 = *(const bf16x8*)(Vs + row * 64 + ((quad) ^ (row & 7)) * 8);
      const bf16x8 v1 = *(const bf16x8*)(Vs + row * 64 + ((4 + quad) ^ (row & 7)) * 8);
      O[d4] = __builtin_amdgcn_mfma_f32_16x16x32_bf16(v0, ap0, O[d4], 0, 0, 0);
      O[d4] = __builtin_amdgcn_mfma_f32_16x16x32_bf16(v1, ap1, O[d4], 0, 0, 0);
    }
  }
  float ls = lsum;
  ls += __shfl_xor(ls, 16);
  ls += __shfl_xor(ls, 32);
  const float inv = 1.0f / ls;  // per-lane correct for q = lm
#pragma unroll
  for (int d4 = 0; d4 < 4; ++d4) {
    uint2 pk;
    pk.x = pack2bf(O[d4][0] * inv, O[d4][1] * inv);
    pk.y = pack2bf(O[d4][2] * inv, O[d4][3] * inv);
    *(uint2*)(ctx + pidx * 512 + h * 64 + d4 * 16 + quad * 4) = pk;
  }
}

// ---------------- LN1 (routed): x1[p] = LN(x[tlist[p]] + ctxp[p]; g1,be1) -> bf16 ----------------
__global__ __launch_bounds__(256) void ln1_kernel(const float* __restrict__ x,
                                                  const u16* __restrict__ ctxp,
                                                  const float* __restrict__ g1,
                                                  const float* __restrict__ be1,
                                                  u16* __restrict__ x1,
                                                  const int* __restrict__ cnt,
                                                  const int* __restrict__ tlist) {
  const int i = blockIdx.x, b = blockIdx.y, e = blockIdx.z;
  const int seg = (e << 2) + b;
  const int ce = (cnt[seg] + 127) & ~127;
  if (i >= ce) return;  // compute all padded rows so downstream GEMM reads defined data
  const long long p = seg * 1024 + i;
  const int t = tlist[p];
  const int tid = threadIdx.x;
  const int wave = tid >> 6, lane = tid & 63;
  __shared__ float sred[4], qred[4];
  const float v0 = x[(long long)t * 512 + tid] + bf2f(ctxp[p * 512 + tid]);
  const float v1 = x[(long long)t * 512 + tid + 256] + bf2f(ctxp[p * 512 + tid + 256]);
  float s = v0 + v1, q = v0 * v0 + v1 * v1;
#pragma unroll
  for (int off = 32; off; off >>= 1) { s += __shfl_xor(s, off); q += __shfl_xor(q, off); }
  if (lane == 0) { sred[wave] = s; qred[wave] = q; }
  __syncthreads();
  s = sred[0] + sred[1] + sred[2] + sred[3];
  q = qred[0] + qred[1] + qred[2] + qred[3];
  const float mean = s * (1.0f / 512.0f);
  const float var = q * (1.0f / 512.0f) - mean * mean;
  const float rstd = rsqrtf(var + 1e-5f);
  x1[p * 512 + tid] = f2bf((v0 - mean) * rstd * g1[e * 512 + tid] + be1[e * 512 + tid]);
  x1[p * 512 + tid + 256] =
      f2bf((v1 - mean) * rstd * g1[e * 512 + tid + 256] + be1[e * 512 + tid + 256]);
}

// ---------------- LN2 + gate-weighted combine: out[t] = sum_e w[t,e]*LN(x1[p]+h2[p]) ----------------
__global__ __launch_bounds__(256) void ln2_kernel(const u16* __restrict__ x1,
                                                  const u16* __restrict__ h2,
                                                  const float* __restrict__ g2,
                                                  const float* __restrict__ be2,
                                                  const float* __restrict__ gated,
                                                  const int* __restrict__ pos,
                                                  float* __restrict__ out) {
  const int t = blockIdx.x, tid = threadIdx.x;
  const int b = t >> 10;
  const int wave = tid >> 6, lane = tid & 63;
  __shared__ float sred[4], qred[4];
  float o0 = 0.f, o1 = 0.f;
  for (int e = 0; e < 8; ++e) {
    const float wgt = gated[t * 8 + e];
    if (wgt != 0.f) {  // block-uniform branch (depends on t only)
      const long long p = ((e << 2) + b) * 1024 + pos[e * 4096 + t];
      const float v0 = bf2f(x1[p * 512 + tid]) + bf2f(h2[p * 512 + tid]);
      const float v1 = bf2f(x1[p * 512 + tid + 256]) + bf2f(h2[p * 512 + tid + 256]);
      float s = v0 + v1, q = v0 * v0 + v1 * v1;
#pragma unroll
      for (int off = 32; off; off >>= 1) { s += __shfl_xor(s, off); q += __shfl_xor(q, off); }
      if (lane == 0) { sred[wave] = s; qred[wave] = q; }
      __syncthreads();
      s = sred[0] + sred[1] + sred[2] + sred[3];
      q = qred[0] + qred[1] + qred[2] + qred[3];
      __syncthreads();
      const float mean = s * (1.0f / 512.0f);
      const float var = q * (1.0f / 512.0f) - mean * mean;
      const float rstd = rsqrtf(var + 1e-5f);
      o0 += wgt * ((v0 - mean) * rstd * g2[e * 512 + tid] + be2[e * 512 + tid]);
      o1 += wgt * ((v1 - mean) * rstd * g2[e * 512 + tid + 256] + be2[e * 512 + tid + 256]);
    }
  }
  out[(long long)t * 512 + tid] = o0;
  out[(long long)t * 512 + tid + 256] = o1;
}

// ---------------- launch ----------------
extern "C" void kernel_launch(void* const* d_in, const int* in_sizes, int n_in, void* d_out,
                              int out_size, void* d_ws, size_t ws_size, hipStream_t stream) {
  const float* x    = (const float*)d_in[0];
  const float* gWk  = (const float*)d_in[1];
  const float* gbk  = (const float*)d_in[2];
  const float* eq   = (const float*)d_in[3];
  const float* Wqkv = (const float*)d_in[4];
  const float* bqkv = (const float*)d_in[5];
  const float* Wo   = (const float*)d_in[6];
  const float* bo   = (const float*)d_in[7];
  const float* g1   = (const float*)d_in[8];
  const float* be1  = (const float*)d_in[9];
  const float* W1   = (const float*)d_in[10];
  const float* bf1  = (const float*)d_in[11];
  const float* W2   = (const float*)d_in[12];
  const float* bf2  = (const float*)d_in[13];
  const float* g2   = (const float*)d_in[14];
  const float* be2  = (const float*)d_in[15];
  float* out = (float*)d_out;

  char* wsp = (char*)d_ws;
  size_t off = 0;
  auto take = [&](size_t bytes) -> void* {
    void* p = wsp + off;
    off += (bytes + 255) & ~(size_t)255;
    return p;
  };
  u16* xb    = (u16*)take((size_t)Mc * 512 * 2);
  u16* Wqkvb = (u16*)take((size_t)Ec * 1536 * 512 * 2);
  u16* Wob   = (u16*)take((size_t)Ec * 512 * 512 * 2);
  u16* W1b   = (u16*)take((size_t)Ec * 2048 * 512 * 2);
  u16* W2b   = (u16*)take((size_t)Ec * 512 * 2048 * 2);
  float* weq   = (float*)take(8 * 512 * 4);
  float* beqb  = (float*)take(8 * 4);
  float* gated = (float*)take((size_t)Mc * 8 * 4);
  int* cnt   = (int*)take(32 * 4);
  int* tlist = (int*)take(32 * 1024 * 4);
  int* pos   = (int*)take((size_t)Ec * Mc * 4);
  int* wl    = (int*)take(512 * 4);
  char* big = (char*)take(134217728);
  u16* qkb  = (u16*)big;                  // [E][M][1024], dead after attn
  u16* vTb  = (u16*)(big + 67108864);     // [E][B][H][64][S], dead after attn
  u16* ctxp = (u16*)(big + 100663296);    // compact [32768][512], dead after ln1
  u16* hb   = (u16*)big;                  // compact [32768][2048], written after ln1
  u16* ctxb = (u16*)take(33554432);       // compact attn out, dead after Wo GEMM
  u16* h2b  = ctxb;                       // compact W2 out, written after W1
  u16* x1b  = (u16*)take(33554432);       // compact [32768][512]
  (void)in_sizes; (void)n_in; (void)out_size; (void)ws_size;

  // fp32 -> bf16 converts
  cvt_kernel<<<dim3(2048), dim3(256), 0, stream>>>(x, xb, (long long)Mc * 512);
  cvt_kernel<<<dim3(6144), dim3(256), 0, stream>>>(Wqkv, Wqkvb, (long long)Ec * 1536 * 512);
  cvt_kernel<<<dim3(2048), dim3(256), 0, stream>>>(Wo, Wob, (long long)Ec * 512 * 512);
  cvt_kernel<<<dim3(8192), dim3(256), 0, stream>>>(W1, W1b, (long long)Ec * 2048 * 512);
  cvt_kernel<<<dim3(8192), dim3(256), 0, stream>>>(W2, W2b, (long long)Ec * 512 * 2048);
  // gating (fp32 path; keys GEMM folded into weq precompute)
  hipMemsetAsync(cnt, 0, 32 * 4, stream);
  weq_kernel<<<dim3(8, 8), dim3(256), 0, stream>>>(gWk, eq, weq);
  beq_kernel<<<dim3(1), dim3(256), 0, stream>>>(gbk, eq, beqb);
  gate_kernel<<<dim3(1024), dim3(256), 0, stream>>>(x, weq, beqb, gated, cnt, tlist, pos);
  pad_kernel<<<dim3(32), dim3(128), 0, stream>>>(cnt, tlist);
  wl_kernel<<<dim3(1), dim3(64), 0, stream>>>(cnt, wl);
  // qkv dense (k,v needed at all tokens) — BK=64
  gemm_bf16<0, 1, 0, 64><<<dim3(32, 12, 8), dim3(256), 0, stream>>>(xb, Wqkvb, bqkv, qkb, vTb, Mc, 1536, 512, 0LL, wl);
  // routed expert pipeline — worklist-compacted grids (active blocks contiguous)
  attn_tile<<<dim3(192, 8), dim3(256), 0, stream>>>(qkb, vTb, ctxb, wl, tlist);
  gemm_bf16<0, 0, 1, 128><<<dim3(96, 4), dim3(256), 0, stream>>>(ctxb, Wob, bo, ctxp, nullptr, Mc, 512, 512, (long long)Mc * 512, wl);
  ln1_kernel<<<dim3(1024, 4, 8), dim3(256), 0, stream>>>(x, ctxp, g1, be1, x1b, cnt, tlist);
  gemm_bf16<1, 0, 1, 128><<<dim3(96, 16), dim3(256), 0, stream>>>(x1b, W1b, bf1, hb, nullptr, Mc, 2048, 512, (long long)Mc * 512, wl);
  gemm_bf16<1, 0, 1, 128><<<dim3(96, 4), dim3(256), 0, stream>>>(hb, W2b, bf2, h2b, nullptr, Mc, 512, 2048, (long long)Mc * 2048, wl);
  ln2_kernel<<<dim3(4096), dim3(256), 0, stream>>>(x1b, h2b, g2, be2, gated, pos, out);
}

// Round 3
// 481.756 us; speedup vs baseline: 1.2676x; 1.0581x over previous
//
#include <hip/hip_runtime.h>
#include <cstdint>
#include <cmath>

// Problem constants (B,S,D,F,E,K,H = 4,1024,512,2048,8,2,8; HEAD_DIM=64)
#define Bc 4
#define Sc 1024
#define Dc 512
#define Fc 2048
#define Ec 8
#define Hc 8
#define Mc 4096  // B*S

typedef unsigned short u16;
typedef __attribute__((ext_vector_type(8))) short bf16x8;  // 8 bf16 = 4 VGPRs
typedef __attribute__((ext_vector_type(4))) float f32x4;

__device__ __forceinline__ float bf2f(u16 u) {
  unsigned v = ((unsigned)u) << 16;
  return __builtin_bit_cast(float, v);
}
__device__ __forceinline__ u16 f2bf(float f) {
  unsigned u = __builtin_bit_cast(unsigned, f);
  unsigned r = 0x7fffu + ((u >> 16) & 1u);
  return (u16)((u + r) >> 16);
}
__device__ __forceinline__ unsigned pack2bf(float a, float b) {
  return (unsigned)f2bf(a) | ((unsigned)f2bf(b) << 16);
}
// tanh-approx GELU (max abs err ~3e-4 vs exact erf-GELU; threshold headroom is ~0.07)
__device__ __forceinline__ float gelu_f(float x) {
  const float z = 1.5957691216057308f * fmaf(0.044715f * x, x * x, x);  // 2*sqrt(2/pi)*(x+c x^3)
  const float e = __expf(z);
  return x * (1.0f - __builtin_amdgcn_rcpf(e + 1.0f));
}
// async global->LDS, 16B per lane; LDS dest = base + lane*16 (wave-uniform base)
__device__ __forceinline__ void async16(const void* g, void* l) {
  __builtin_amdgcn_global_load_lds(
      (const __attribute__((address_space(1))) unsigned int*)g,
      (__attribute__((address_space(3))) unsigned int*)l, 16, 0, 0);
}

// fused f32 -> bf16 conversion for all 5 input tensors (single launch; each block does 1024 elems)
__global__ __launch_bounds__(256) void cvt5_kernel(const float* __restrict__ p0, u16* __restrict__ q0,
                                                   const float* __restrict__ p1, u16* __restrict__ q1,
                                                   const float* __restrict__ p2, u16* __restrict__ q2,
                                                   const float* __restrict__ p3, u16* __restrict__ q3,
                                                   const float* __restrict__ p4, u16* __restrict__ q4) {
  int bx = blockIdx.x;
  const float* in;
  u16* outp;
  if (bx < 2048) { in = p0; outp = q0; }                       // x: 2,097,152
  else if (bx < 8192) { in = p1; outp = q1; bx -= 2048; }      // Wqkv: 6,291,456
  else if (bx < 10240) { in = p2; outp = q2; bx -= 8192; }     // Wo: 2,097,152
  else if (bx < 18432) { in = p3; outp = q3; bx -= 10240; }    // W1: 8,388,608
  else { in = p4; outp = q4; bx -= 18432; }                    // W2: 8,388,608
  const long long i = ((long long)bx * 256 + threadIdx.x) * 4;
  const float4 v = *(const float4*)(in + i);
  ushort4 o;
  o.x = f2bf(v.x); o.y = f2bf(v.y); o.z = f2bf(v.z); o.w = f2bf(v.w);
  *(ushort4*)(outp + i) = o;
}

// ---------------- gating precompute: weq[e][d] = sum_j eq[e][j] * gWk[j][d] ----------------
__global__ __launch_bounds__(256) void weq_kernel(const float* __restrict__ gWk,
                                                  const float* __restrict__ eq,
                                                  float* __restrict__ weq) {
  __shared__ float red[4][64];
  const int tid = threadIdx.x, wave = tid >> 6, lane = tid & 63;
  const int d = blockIdx.x * 64 + lane;
  const int e = blockIdx.y;
  float acc = 0.f;
  for (int j = wave * 128; j < wave * 128 + 128; ++j)
    acc += gWk[(long long)j * 512 + d] * eq[e * 512 + j];
  red[wave][lane] = acc;
  __syncthreads();
  if (wave == 0)
    weq[e * 512 + d] = red[0][lane] + red[1][lane] + red[2][lane] + red[3][lane];
}
__global__ void beq_kernel(const float* __restrict__ gbk, const float* __restrict__ eq,
                           float* __restrict__ beq) {
  const int wave = threadIdx.x >> 6, lane = threadIdx.x & 63;
  for (int e = wave; e < 8; e += 4) {
    float a = 0.f;
#pragma unroll
    for (int i = 0; i < 8; ++i) a += gbk[lane + 64 * i] * eq[e * 512 + lane + 64 * i];
#pragma unroll
    for (int off = 32; off; off >>= 1) a += __shfl_xor(a, off);
    if (lane == 0) beq[e] = a;
  }
}

// ---- gating: scores = (x@weq^T + beq)*D^-0.5, softmax(E=8), top-2, renorm; build routing lists --
__global__ __launch_bounds__(256) void gate_kernel(const float* __restrict__ x,
                                                   const float* __restrict__ weq,
                                                   const float* __restrict__ beq,
                                                   float* __restrict__ gated,
                                                   int* __restrict__ cnt, int* __restrict__ tlist,
                                                   int* __restrict__ pos) {
  const int wave = threadIdx.x >> 6, lane = threadIdx.x & 63;
  const int t = blockIdx.x * 4 + wave;
  const float* xr = x + (long long)t * 512;
  float acc[8] = {};
#pragma unroll
  for (int i = 0; i < 8; ++i) {
    const float xv = xr[lane + 64 * i];
#pragma unroll
    for (int e2 = 0; e2 < 8; ++e2) acc[e2] += xv * weq[e2 * 512 + lane + 64 * i];
  }
#pragma unroll
  for (int e2 = 0; e2 < 8; ++e2)
#pragma unroll
    for (int off = 32; off; off >>= 1) acc[e2] += __shfl_xor(acc[e2], off);
  if (lane == 0) {
    const float scale = 0.044194173824159216f;  // 512^-0.5
    float s[8], mx = -1e30f;
#pragma unroll
    for (int e2 = 0; e2 < 8; ++e2) { s[e2] = (acc[e2] + beq[e2]) * scale; mx = fmaxf(mx, s[e2]); }
    float p[8], sum = 0.f;
#pragma unroll
    for (int e2 = 0; e2 < 8; ++e2) { p[e2] = expf(s[e2] - mx); sum += p[e2]; }
#pragma unroll
    for (int e2 = 0; e2 < 8; ++e2) p[e2] /= sum;
    int i1 = 0;
#pragma unroll
    for (int e2 = 1; e2 < 8; ++e2) if (p[e2] > p[i1]) i1 = e2;
    int i2 = (i1 == 0) ? 1 : 0;
#pragma unroll
    for (int e2 = 0; e2 < 8; ++e2) if (e2 != i1 && e2 != i2 && p[e2] > p[i2]) i2 = e2;
    const float denom = p[i1] + p[i2] + 1e-9f;
#pragma unroll
    for (int e2 = 0; e2 < 8; ++e2)
      gated[t * 8 + e2] = (e2 == i1 || e2 == i2) ? p[e2] / denom : 0.f;
    const int b = t >> 10;
    int s1 = atomicAdd(cnt + i1 * 4 + b, 1);
    tlist[(i1 * 4 + b) * 1024 + s1] = t;
    pos[i1 * 4096 + t] = s1;
    int s2 = atomicAdd(cnt + i2 * 4 + b, 1);
    tlist[(i2 * 4 + b) * 1024 + s2] = t;
    pos[i2 * 4096 + t] = s2;
  }
}

// pad each (e,b) segment of tlist to a multiple of 128 with a valid token (row 0 of sequence b)
__global__ void pad_kernel(const int* __restrict__ cnt, int* __restrict__ tlist) {
  const int seg = blockIdx.x;
  const int c = cnt[seg];
  const int ce = (c + 127) & ~127;
  const int tpad = (seg & 3) << 10;
  for (int i = c + (int)threadIdx.x; i < ce; i += 128) tlist[seg * 1024 + i] = tpad;
}

// ---- work lists: compact (seg,tile) items so active blocks are CONTIGUOUS in linear ----
// ---- block id (spreads across all 8 XCDs). wl[0..95]: 128-row GEMM tiles, total at  ----
// ---- wl[96]. wl[128..319]: 64-row attn q-tiles, total at wl[97].                    ----
__global__ void wl_kernel(const int* __restrict__ cnt, int* __restrict__ wl) {
  const int seg = threadIdx.x;
  if (seg >= 32) return;
  int base = 0;
  for (int s = 0; s < seg; ++s) base += (cnt[s] + 127) >> 7;
  const int nt = (cnt[seg] + 127) >> 7;
  for (int t = 0; t < nt; ++t) wl[base + t] = (seg << 8) | t;
  for (int t = 0; t < 2 * nt; ++t) wl[128 + 2 * base + t] = (seg << 8) | t;
  if (seg == 31) { wl[96] = base + nt; wl[97] = 2 * (base + nt); }
}

// ---------------- bf16 MFMA GEMM: C[m,n] = sum_k A[m,k]*Bt[n,k] + bias[n] ----------------
// 128x128 tile, BK in {64,128}, 4 waves each 64x64 (4x4 of 16x16x32 MFMA), operand-swapped
// epilogue. ROUTED reads its (expert, bseg, tile) from the compacted work list wl.
// GATHER: A rows are gathered through tlist (token indices, hoisted before the K-loop).
// QKV epilogue: n0<512 -> k packed [e][t][512]; else v transposed [e][b][h][64][S].
template <int GELU, int QKV, int ROUTED, int BK, int GATHER>
__global__ __launch_bounds__(256) void gemm_bf16(
    const u16* __restrict__ A, const u16* __restrict__ Bw, const float* __restrict__ bias,
    u16* __restrict__ Cout, u16* __restrict__ vT, int M, int N, int K, long long Astride,
    long long Bstride, const int* __restrict__ wl, const int* __restrict__ tlist) {
  int e;
  long long bm;
  if (ROUTED) {
    const int total = wl[96];
    if ((int)blockIdx.x >= total) return;
    const int item = wl[blockIdx.x];
    const int seg = item >> 8, tile = item & 255;
    e = seg >> 2;
    bm = ((long long)(seg & 3) << 10) + tile * 128;
  } else {
    e = blockIdx.z;
    bm = (long long)blockIdx.x * 128;
  }
  __shared__ __attribute__((aligned(16))) u16 As[128 * BK];
  __shared__ __attribute__((aligned(16))) u16 Bs[128 * BK];
  const int tid = threadIdx.x;
  const int wave = tid >> 6, lane = tid & 63;
  const long long bn = (long long)blockIdx.y * 128;
  const u16* Ag = A + (long long)e * Astride + bm * K;
  const u16* Bg = Bw + ((long long)e * Bstride + bn) * K;
  constexpr int LPR = BK / 8;   // lanes per row in a staging instruction
  constexpr int RPI = 512 / BK; // rows per staging instruction
  constexpr int IPW = BK / 16;  // staging instructions per wave (each of A and B)
  const int lrow = lane / LPR, lpos = lane % LPR;
  const int lm = lane & 15, quad = lane >> 4;
  const int wm = (wave >> 1) * 64, wn = (wave & 1) * 64;
  int tok[IPW];
  if (GATHER) {
    const long long tbase = (long long)e * 4096 + bm;
#pragma unroll
    for (int i = 0; i < IPW; ++i) {
      const int gi = wave * IPW + i;
      tok[i] = tlist[tbase + gi * RPI + lrow];
    }
  }
  f32x4 acc[4][4] = {};
  for (int kk = 0; kk < K; kk += BK) {
    __syncthreads();
#pragma unroll
    for (int i = 0; i < IPW; ++i) {
      const int gi = wave * IPW + i;        // instruction slot 0..BK/4-1
      const int row = gi * RPI + lrow;      // tile row 0..127
      const int sc = lpos ^ (row & 7);      // XOR-swizzled source chunk
      if (GATHER)
        async16(A + (long long)tok[i] * K + kk + sc * 8, &As[gi * 512]);
      else
        async16(Ag + (long long)row * K + kk + sc * 8, &As[gi * 512]);
      async16(Bg + (long long)row * K + kk + sc * 8, &Bs[gi * 512]);
    }
    __syncthreads();
#pragma unroll
    for (int ks = 0; ks < BK / 32; ++ks) {
      bf16x8 af[4], bfr[4];
#pragma unroll
      for (int mi = 0; mi < 4; ++mi) {
        const int row = wm + mi * 16 + lm;
        const int ch = (ks * 4 + quad) ^ (row & 7);
        af[mi] = *(const bf16x8*)(As + row * BK + ch * 8);
      }
#pragma unroll
      for (int nj = 0; nj < 4; ++nj) {
        const int row = wn + nj * 16 + lm;
        const int ch = (ks * 4 + quad) ^ (row & 7);
        bfr[nj] = *(const bf16x8*)(Bs + row * BK + ch * 8);
      }
#pragma unroll
      for (int mi = 0; mi < 4; ++mi)
#pragma unroll
        for (int nj = 0; nj < 4; ++nj)
          acc[mi][nj] = __builtin_amdgcn_mfma_f32_16x16x32_bf16(bfr[nj], af[mi], acc[mi][nj], 0, 0, 0);
    }
  }
  // Epilogue: lane owns row m = bm+wm+mi*16+lm, 4 consecutive cols n0 = bn+wn+nj*16+quad*4
  const float* bs = bias + (long long)e * Bstride;
#pragma unroll
  for (int mi = 0; mi < 4; ++mi) {
    const int m = (int)bm + wm + mi * 16 + lm;
#pragma unroll
    for (int nj = 0; nj < 4; ++nj) {
      const int n0 = (int)bn + wn + nj * 16 + quad * 4;
      const float4 bv = *(const float4*)(bs + n0);
      float v0 = acc[mi][nj][0] + bv.x;
      float v1 = acc[mi][nj][1] + bv.y;
      float v2 = acc[mi][nj][2] + bv.z;
      float v3 = acc[mi][nj][3] + bv.w;
      if (GELU) { v0 = gelu_f(v0); v1 = gelu_f(v1); v2 = gelu_f(v2); v3 = gelu_f(v3); }
      if (QKV) {
        if (n0 < 512) {  // k packed [e][t][512] (branch uniform per block-y)
          uint2 pk; pk.x = pack2bf(v0, v1); pk.y = pack2bf(v2, v3);
          *(uint2*)(Cout + ((long long)e * Mc + m) * 512 + n0) = pk;
        } else {  // v stored transposed [e][b][h][64][S]; 4 consecutive d -> 4 rows
          const int hh = (n0 - 512) >> 6, dd = (n0 - 512) & 63;
          const int bb = m >> 10, ss = m & 1023;
          u16* vp = vT + ((((long long)e * Bc + bb) * Hc + hh) * 64 + dd) * Sc + ss;
          vp[0] = f2bf(v0); vp[Sc] = f2bf(v1); vp[2 * Sc] = f2bf(v2); vp[3 * Sc] = f2bf(v3);
        }
      } else {
        uint2 pk; pk.x = pack2bf(v0, v1); pk.y = pack2bf(v2, v3);
        *(uint2*)(Cout + ((long long)e * M + m) * N + n0) = pk;
      }
    }
  }
}

// -------- flash attention: ONE block per (q-tile, head) from the q worklist. --------
// 64 q rows per block; Q read from the compact routed buffer qb (no tlist indirection),
// K from kb [e][t][512], V transposed. K/V chunk re-reads across blocks hit L2.
__global__ __launch_bounds__(256, 4) void attn_tile(const u16* __restrict__ qb,
                                                    const u16* __restrict__ kb,
                                                    const u16* __restrict__ vT,
                                                    u16* __restrict__ ctx,
                                                    const int* __restrict__ wl) {
  if ((int)blockIdx.x >= wl[97]) return;
  const int item = wl[128 + blockIdx.x];
  const int seg = item >> 8, qt = item & 255;
  const int e = seg >> 2, b = seg & 3, h = blockIdx.y;
  __shared__ __attribute__((aligned(16))) u16 Ks[64 * 64];     // [key][d] swizzled
  __shared__ __attribute__((aligned(16))) u16 Vs[64 * 64];     // [d][key] swizzled
  __shared__ __attribute__((aligned(16))) u16 Pl[4][16 * 72];  // per-wave P[q][key], stride 72
  const int tid = threadIdx.x, wave = tid >> 6, lane = tid & 63;
  const int lm = lane & 15, quad = lane >> 4;
  const u16* kbase = kb + ((long long)e * Mc + b * Sc) * 512;
  const u16* vbase = vT + ((((long long)e * Bc + b) * Hc + h) * 64) * Sc;
  const int lr = lane >> 3, lc = (lane & 7) ^ lr;
  u16* P = &Pl[wave][0];
  unsigned* P32 = (unsigned*)P;
  const int pwbase = lm * 36 + quad * 2;  // dword index of this lane's P writes

  // q fragments for this lane's 16 rows (routed position pidx, compact layout)
  const long long pidx = (long long)seg * 1024 + qt * 64 + wave * 16 + lm;
  bf16x8 aq[2];
#pragma unroll
  for (int ks = 0; ks < 2; ++ks)
    aq[ks] = *(const bf16x8*)(qb + pidx * 512 + h * 64 + ks * 32 + quad * 8);
  f32x4 O[4] = {};
  float lsum = 0.f;

  for (int n0 = 0; n0 < Sc; n0 += 64) {
    __syncthreads();
#pragma unroll
    for (int i = 0; i < 2; ++i) {
      const int rg = wave * 2 + i;  // 0..7
      const int row = rg * 8 + lr;  // 0..63
      async16(kbase + (long long)(n0 + row) * 512 + h * 64 + lc * 8, &Ks[rg * 512]);
      async16(vbase + (long long)row * Sc + n0 + lc * 8, &Vs[rg * 512]);
    }
    __syncthreads();
    // S^T = K @ Q^T : C-layout row = key = kj*16 + quad*4 + r, col = q = lm
    f32x4 sT[4];
#pragma unroll
    for (int kj = 0; kj < 4; ++kj) {
      const int row = kj * 16 + lm;
      const bf16x8 k0 = *(const bf16x8*)(Ks + row * 64 + ((quad) ^ (row & 7)) * 8);
      const bf16x8 k1 = *(const bf16x8*)(Ks + row * 64 + ((4 + quad) ^ (row & 7)) * 8);
      f32x4 c = {};
      c = __builtin_amdgcn_mfma_f32_16x16x32_bf16(k0, aq[0], c, 0, 0, 0);
      c = __builtin_amdgcn_mfma_f32_16x16x32_bf16(k1, aq[1], c, 0, 0, 0);
      sT[kj] = c;
    }
    // p = exp(s/8) (scores bounded -> no running-max rescale); local denom
#pragma unroll
    for (int kj = 0; kj < 4; ++kj) {
      const float p0 = __expf(sT[kj][0] * 0.125f);
      const float p1 = __expf(sT[kj][1] * 0.125f);
      const float p2 = __expf(sT[kj][2] * 0.125f);
      const float p3 = __expf(sT[kj][3] * 0.125f);
      lsum += (p0 + p1) + (p2 + p3);
      P32[pwbase + kj * 8 + 0] = pack2bf(p0, p1);
      P32[pwbase + kj * 8 + 1] = pack2bf(p2, p3);
    }
    asm volatile("s_waitcnt lgkmcnt(0)" ::: "memory");
    const bf16x8 ap0 = *(const bf16x8*)(P + lm * 72 + quad * 8);
    const bf16x8 ap1 = *(const bf16x8*)(P + lm * 72 + 32 + quad * 8);
    // PV: O^T[d][q] += V^T[d][key] * P[q][key]
#pragma unroll
    for (int d4 = 0; d4 < 4; ++d4) {
      const int row = d4 * 16 + lm;
      const bf16x8 v0 = *(const bf16x8*)(Vs + row * 64 + ((quad) ^ (row & 7)) * 8);
      const bf16x8 v1 = *(const bf16x8*)(Vs + row * 64 + ((4 + quad) ^ (row & 7)) * 8);
      O[d4] = __builtin_amdgcn_mfma_f32_16x16x32_bf16(v0, ap0, O[d4], 0, 0, 0);
      O[d4] = __builtin_amdgcn_mfma_f32_16x16x32_bf16(v1, ap1, O[d4], 0, 0, 0);
    }
  }
  float ls = lsum;
  ls += __shfl_xor(ls, 16);
  ls += __shfl_xor(ls, 32);
  const float inv = 1.0f / ls;  // per-lane correct for q = lm
#pragma unroll
  for (int d4 = 0; d4 < 4; ++d4) {
    uint2 pk;
    pk.x = pack2bf(O[d4][0] * inv, O[d4][1] * inv);
    pk.y = pack2bf(O[d4][2] * inv, O[d4][3] * inv);
    *(uint2*)(ctx + pidx * 512 + h * 64 + d4 * 16 + quad * 4) = pk;
  }
}

// ---------------- LN1 (routed): x1[p] = LN(x[tlist[p]] + ctxp[p]; g1,be1) -> bf16 ----------------
__global__ __launch_bounds__(256) void ln1_kernel(const float* __restrict__ x,
                                                  const u16* __restrict__ ctxp,
                                                  const float* __restrict__ g1,
                                                  const float* __restrict__ be1,
                                                  u16* __restrict__ x1,
                                                  const int* __restrict__ cnt,
                                                  const int* __restrict__ tlist) {
  const int i = blockIdx.x, b = blockIdx.y, e = blockIdx.z;
  const int seg = (e << 2) + b;
  const int ce = (cnt[seg] + 127) & ~127;
  if (i >= ce) return;  // compute all padded rows so downstream GEMM reads defined data
  const long long p = seg * 1024 + i;
  const int t = tlist[p];
  const int tid = threadIdx.x;
  const int wave = tid >> 6, lane = tid & 63;
  __shared__ float sred[4], qred[4];
  const float v0 = x[(long long)t * 512 + tid] + bf2f(ctxp[p * 512 + tid]);
  const float v1 = x[(long long)t * 512 + tid + 256] + bf2f(ctxp[p * 512 + tid + 256]);
  float s = v0 + v1, q = v0 * v0 + v1 * v1;
#pragma unroll
  for (int off = 32; off; off >>= 1) { s += __shfl_xor(s, off); q += __shfl_xor(q, off); }
  if (lane == 0) { sred[wave] = s; qred[wave] = q; }
  __syncthreads();
  s = sred[0] + sred[1] + sred[2] + sred[3];
  q = qred[0] + qred[1] + qred[2] + qred[3];
  const float mean = s * (1.0f / 512.0f);
  const float var = q * (1.0f / 512.0f) - mean * mean;
  const float rstd = rsqrtf(var + 1e-5f);
  x1[p * 512 + tid] = f2bf((v0 - mean) * rstd * g1[e * 512 + tid] + be1[e * 512 + tid]);
  x1[p * 512 + tid + 256] =
      f2bf((v1 - mean) * rstd * g1[e * 512 + tid + 256] + be1[e * 512 + tid + 256]);
}

// ---------------- LN2 + gate-weighted combine: out[t] = sum_e w[t,e]*LN(x1[p]+h2[p]) ----------------
__global__ __launch_bounds__(256) void ln2_kernel(const u16* __restrict__ x1,
                                                  const u16* __restrict__ h2,
                                                  const float* __restrict__ g2,
                                                  const float* __restrict__ be2,
                                                  const float* __restrict__ gated,
                                                  const int* __restrict__ pos,
                                                  float* __restrict__ out) {
  const int t = blockIdx.x, tid = threadIdx.x;
  const int b = t >> 10;
  const int wave = tid >> 6, lane = tid & 63;
  __shared__ float sred[4], qred[4];
  float o0 = 0.f, o1 = 0.f;
  for (int e = 0; e < 8; ++e) {
    const float wgt = gated[t * 8 + e];
    if (wgt != 0.f) {  // block-uniform branch (depends on t only)
      const long long p = ((e << 2) + b) * 1024 + pos[e * 4096 + t];
      const float v0 = bf2f(x1[p * 512 + tid]) + bf2f(h2[p * 512 + tid]);
      const float v1 = bf2f(x1[p * 512 + tid + 256]) + bf2f(h2[p * 512 + tid + 256]);
      float s = v0 + v1, q = v0 * v0 + v1 * v1;
#pragma unroll
      for (int off = 32; off; off >>= 1) { s += __shfl_xor(s, off); q += __shfl_xor(q, off); }
      if (lane == 0) { sred[wave] = s; qred[wave] = q; }
      __syncthreads();
      s = sred[0] + sred[1] + sred[2] + sred[3];
      q = qred[0] + qred[1] + qred[2] + qred[3];
      __syncthreads();
      const float mean = s * (1.0f / 512.0f);
      const float var = q * (1.0f / 512.0f) - mean * mean;
      const float rstd = rsqrtf(var + 1e-5f);
      o0 += wgt * ((v0 - mean) * rstd * g2[e * 512 + tid] + be2[e * 512 + tid]);
      o1 += wgt * ((v1 - mean) * rstd * g2[e * 512 + tid + 256] + be2[e * 512 + tid + 256]);
    }
  }
  out[(long long)t * 512 + tid] = o0;
  out[(long long)t * 512 + tid + 256] = o1;
}

// ---------------- launch ----------------
extern "C" void kernel_launch(void* const* d_in, const int* in_sizes, int n_in, void* d_out,
                              int out_size, void* d_ws, size_t ws_size, hipStream_t stream) {
  const float* x    = (const float*)d_in[0];
  const float* gWk  = (const float*)d_in[1];
  const float* gbk  = (const float*)d_in[2];
  const float* eq   = (const float*)d_in[3];
  const float* Wqkv = (const float*)d_in[4];
  const float* bqkv = (const float*)d_in[5];
  const float* Wo   = (const float*)d_in[6];
  const float* bo   = (const float*)d_in[7];
  const float* g1   = (const float*)d_in[8];
  const float* be1  = (const float*)d_in[9];
  const float* W1   = (const float*)d_in[10];
  const float* bf1  = (const float*)d_in[11];
  const float* W2   = (const float*)d_in[12];
  const float* bf2  = (const float*)d_in[13];
  const float* g2   = (const float*)d_in[14];
  const float* be2  = (const float*)d_in[15];
  float* out = (float*)d_out;

  char* wsp = (char*)d_ws;
  size_t off = 0;
  auto take = [&](size_t bytes) -> void* {
    void* p = wsp + off;
    off += (bytes + 255) & ~(size_t)255;
    return p;
  };
  u16* xb    = (u16*)take((size_t)Mc * 512 * 2);
  u16* Wqkvb = (u16*)take((size_t)Ec * 1536 * 512 * 2);
  u16* Wob   = (u16*)take((size_t)Ec * 512 * 512 * 2);
  u16* W1b   = (u16*)take((size_t)Ec * 2048 * 512 * 2);
  u16* W2b   = (u16*)take((size_t)Ec * 512 * 2048 * 2);
  float* weq   = (float*)take(8 * 512 * 4);
  float* beqb  = (float*)take(8 * 4);
  float* gated = (float*)take((size_t)Mc * 8 * 4);
  int* cnt   = (int*)take(32 * 4);
  int* tlist = (int*)take(32 * 1024 * 4);
  int* pos   = (int*)take((size_t)Ec * Mc * 4);
  int* wl    = (int*)take(512 * 4);
  char* big = (char*)take(134217728);
  u16* qb   = (u16*)big;                  // compact q [32768][512], dead after attn
  u16* kb   = (u16*)(big + 33554432);     // k [E][M][512], dead after attn
  u16* vTb  = (u16*)(big + 67108864);     // [E][B][H][64][S], dead after attn
  u16* ctxp = (u16*)(big + 100663296);    // compact [32768][512], dead after ln1
  u16* hb   = (u16*)big;                  // compact [32768][2048], written after ln1
  u16* ctxb = (u16*)take(33554432);       // compact attn out, dead after Wo GEMM
  u16* h2b  = ctxb;                       // compact W2 out, written after W1
  u16* x1b  = (u16*)take(33554432);       // compact [32768][512]
  (void)in_sizes; (void)n_in; (void)out_size; (void)ws_size;

  // fp32 -> bf16 converts (single fused launch)
  cvt5_kernel<<<dim3(26624), dim3(256), 0, stream>>>(x, xb, Wqkv, Wqkvb, Wo, Wob, W1, W1b, W2, W2b);
  // gating (fp32 path; keys GEMM folded into weq precompute)
  hipMemsetAsync(cnt, 0, 32 * 4, stream);
  weq_kernel<<<dim3(8, 8), dim3(256), 0, stream>>>(gWk, eq, weq);
  beq_kernel<<<dim3(1), dim3(256), 0, stream>>>(gbk, eq, beqb);
  gate_kernel<<<dim3(1024), dim3(256), 0, stream>>>(x, weq, beqb, gated, cnt, tlist, pos);
  pad_kernel<<<dim3(32), dim3(128), 0, stream>>>(cnt, tlist);
  wl_kernel<<<dim3(1), dim3(64), 0, stream>>>(cnt, wl);
  // kv dense (k,v needed at all tokens; q only at routed rows) — N=1024, BK=64
  gemm_bf16<0, 1, 0, 64, 0><<<dim3(32, 8, 8), dim3(256), 0, stream>>>(
      xb, Wqkvb + 512 * 512, bqkv + 512, kb, vTb, Mc, 1024, 512, 0LL, 1536LL, wl, nullptr);
  // q routed (A rows gathered through tlist), compact output
  gemm_bf16<0, 0, 1, 128, 1><<<dim3(96, 4), dim3(256), 0, stream>>>(
      xb, Wqkvb, bqkv, qb, nullptr, Mc, 512, 512, 0LL, 1536LL, wl, tlist);
  // routed expert pipeline — worklist-compacted grids (active blocks contiguous)
  attn_tile<<<dim3(192, 8), dim3(256), 0, stream>>>(qb, kb, vTb, ctxb, wl);
  gemm_bf16<0, 0, 1, 128, 0><<<dim3(96, 4), dim3(256), 0, stream>>>(
      ctxb, Wob, bo, ctxp, nullptr, Mc, 512, 512, (long long)Mc * 512, 512LL, wl, nullptr);
  ln1_kernel<<<dim3(1024, 4, 8), dim3(256), 0, stream>>>(x, ctxp, g1, be1, x1b, cnt, tlist);
  gemm_bf16<1, 0, 1, 128, 0><<<dim3(96, 16), dim3(256), 0, stream>>>(
      x1b, W1b, bf1, hb, nullptr, Mc, 2048, 512, (long long)Mc * 512, 2048LL, wl, nullptr);
  gemm_bf16<1, 0, 1, 128, 0><<<dim3(96, 4), dim3(256), 0, stream>>>(
      hb, W2b, bf2, h2b, nullptr, Mc, 512, 2048, (long long)Mc * 2048, 512LL, wl, nullptr);
  ln2_kernel<<<dim3(4096), dim3(256), 0, stream>>>(x1b, h2b, g2, be2, gated, pos, out);
}

// Round 4
// 473.056 us; speedup vs baseline: 1.2909x; 1.0184x over previous
//
#include <hip/hip_runtime.h>
#include <cstdint>
#include <cmath>

// Problem constants (B,S,D,F,E,K,H = 4,1024,512,2048,8,2,8; HEAD_DIM=64)
#define Bc 4
#define Sc 1024
#define Dc 512
#define Fc 2048
#define Ec 8
#define Hc 8
#define Mc 4096  // B*S

typedef unsigned short u16;
typedef __attribute__((ext_vector_type(8))) short bf16x8;  // 8 bf16 = 4 VGPRs
typedef __attribute__((ext_vector_type(4))) float f32x4;

__device__ __forceinline__ float bf2f(u16 u) {
  unsigned v = ((unsigned)u) << 16;
  return __builtin_bit_cast(float, v);
}
__device__ __forceinline__ u16 f2bf(float f) {
  unsigned u = __builtin_bit_cast(unsigned, f);
  unsigned r = 0x7fffu + ((u >> 16) & 1u);
  return (u16)((u + r) >> 16);
}
__device__ __forceinline__ unsigned pack2bf(float a, float b) {
  return (unsigned)f2bf(a) | ((unsigned)f2bf(b) << 16);
}
// tanh-approx GELU (max abs err ~3e-4 vs exact erf-GELU; threshold headroom is ~0.07)
__device__ __forceinline__ float gelu_f(float x) {
  const float z = 1.5957691216057308f * fmaf(0.044715f * x, x * x, x);  // 2*sqrt(2/pi)*(x+c x^3)
  const float e = __expf(z);
  return x * (1.0f - __builtin_amdgcn_rcpf(e + 1.0f));
}
// async global->LDS, 16B per lane; LDS dest = base + lane*16 (wave-uniform base)
__device__ __forceinline__ void async16(const void* g, void* l) {
  __builtin_amdgcn_global_load_lds(
      (const __attribute__((address_space(1))) unsigned int*)g,
      (__attribute__((address_space(3))) unsigned int*)l, 16, 0, 0);
}

// fused f32 -> bf16 conversion for all 5 input tensors (single launch; each block does 1024 elems)
__global__ __launch_bounds__(256) void cvt5_kernel(const float* __restrict__ p0, u16* __restrict__ q0,
                                                   const float* __restrict__ p1, u16* __restrict__ q1,
                                                   const float* __restrict__ p2, u16* __restrict__ q2,
                                                   const float* __restrict__ p3, u16* __restrict__ q3,
                                                   const float* __restrict__ p4, u16* __restrict__ q4) {
  int bx = blockIdx.x;
  const float* in;
  u16* outp;
  if (bx < 2048) { in = p0; outp = q0; }                       // x: 2,097,152
  else if (bx < 8192) { in = p1; outp = q1; bx -= 2048; }      // Wqkv: 6,291,456
  else if (bx < 10240) { in = p2; outp = q2; bx -= 8192; }     // Wo: 2,097,152
  else if (bx < 18432) { in = p3; outp = q3; bx -= 10240; }    // W1: 8,388,608
  else { in = p4; outp = q4; bx -= 18432; }                    // W2: 8,388,608
  const long long i = ((long long)bx * 256 + threadIdx.x) * 4;
  const float4 v = *(const float4*)(in + i);
  ushort4 o;
  o.x = f2bf(v.x); o.y = f2bf(v.y); o.z = f2bf(v.z); o.w = f2bf(v.w);
  *(ushort4*)(outp + i) = o;
}

// ---------------- gating precompute: weq[e][d] = sum_j eq[e][j] * gWk[j][d] ----------------
__global__ __launch_bounds__(256) void weq_kernel(const float* __restrict__ gWk,
                                                  const float* __restrict__ eq,
                                                  float* __restrict__ weq) {
  __shared__ float red[4][64];
  const int tid = threadIdx.x, wave = tid >> 6, lane = tid & 63;
  const int d = blockIdx.x * 64 + lane;
  const int e = blockIdx.y;
  float acc = 0.f;
  for (int j = wave * 128; j < wave * 128 + 128; ++j)
    acc += gWk[(long long)j * 512 + d] * eq[e * 512 + j];
  red[wave][lane] = acc;
  __syncthreads();
  if (wave == 0)
    weq[e * 512 + d] = red[0][lane] + red[1][lane] + red[2][lane] + red[3][lane];
}
__global__ void beq_kernel(const float* __restrict__ gbk, const float* __restrict__ eq,
                           float* __restrict__ beq) {
  const int wave = threadIdx.x >> 6, lane = threadIdx.x & 63;
  for (int e = wave; e < 8; e += 4) {
    float a = 0.f;
#pragma unroll
    for (int i = 0; i < 8; ++i) a += gbk[lane + 64 * i] * eq[e * 512 + lane + 64 * i];
#pragma unroll
    for (int off = 32; off; off >>= 1) a += __shfl_xor(a, off);
    if (lane == 0) beq[e] = a;
  }
}

// ---- gating: scores = (x@weq^T + beq)*D^-0.5, softmax(E=8), top-2, renorm; build routing lists --
__global__ __launch_bounds__(256) void gate_kernel(const float* __restrict__ x,
                                                   const float* __restrict__ weq,
                                                   const float* __restrict__ beq,
                                                   float* __restrict__ gated,
                                                   int* __restrict__ cnt, int* __restrict__ tlist,
                                                   int* __restrict__ pos) {
  const int wave = threadIdx.x >> 6, lane = threadIdx.x & 63;
  const int t = blockIdx.x * 4 + wave;
  const float* xr = x + (long long)t * 512;
  float acc[8] = {};
#pragma unroll
  for (int i = 0; i < 8; ++i) {
    const float xv = xr[lane + 64 * i];
#pragma unroll
    for (int e2 = 0; e2 < 8; ++e2) acc[e2] += xv * weq[e2 * 512 + lane + 64 * i];
  }
#pragma unroll
  for (int e2 = 0; e2 < 8; ++e2)
#pragma unroll
    for (int off = 32; off; off >>= 1) acc[e2] += __shfl_xor(acc[e2], off);
  if (lane == 0) {
    const float scale = 0.044194173824159216f;  // 512^-0.5
    float s[8], mx = -1e30f;
#pragma unroll
    for (int e2 = 0; e2 < 8; ++e2) { s[e2] = (acc[e2] + beq[e2]) * scale; mx = fmaxf(mx, s[e2]); }
    float p[8], sum = 0.f;
#pragma unroll
    for (int e2 = 0; e2 < 8; ++e2) { p[e2] = expf(s[e2] - mx); sum += p[e2]; }
#pragma unroll
    for (int e2 = 0; e2 < 8; ++e2) p[e2] /= sum;
    int i1 = 0;
#pragma unroll
    for (int e2 = 1; e2 < 8; ++e2) if (p[e2] > p[i1]) i1 = e2;
    int i2 = (i1 == 0) ? 1 : 0;
#pragma unroll
    for (int e2 = 0; e2 < 8; ++e2) if (e2 != i1 && e2 != i2 && p[e2] > p[i2]) i2 = e2;
    const float denom = p[i1] + p[i2] + 1e-9f;
#pragma unroll
    for (int e2 = 0; e2 < 8; ++e2)
      gated[t * 8 + e2] = (e2 == i1 || e2 == i2) ? p[e2] / denom : 0.f;
    const int b = t >> 10;
    int s1 = atomicAdd(cnt + i1 * 4 + b, 1);
    tlist[(i1 * 4 + b) * 1024 + s1] = t;
    pos[i1 * 4096 + t] = s1;
    int s2 = atomicAdd(cnt + i2 * 4 + b, 1);
    tlist[(i2 * 4 + b) * 1024 + s2] = t;
    pos[i2 * 4096 + t] = s2;
  }
}

// pad each (e,b) segment of tlist to a multiple of 128 with a valid token (row 0 of sequence b)
__global__ void pad_kernel(const int* __restrict__ cnt, int* __restrict__ tlist) {
  const int seg = blockIdx.x;
  const int c = cnt[seg];
  const int ce = (c + 127) & ~127;
  const int tpad = (seg & 3) << 10;
  for (int i = c + (int)threadIdx.x; i < ce; i += 128) tlist[seg * 1024 + i] = tpad;
}

// ---- work lists: compact (seg,tile) items so active blocks are CONTIGUOUS in linear ----
// ---- block id (spreads across all 8 XCDs). wl[0..95]: 128-row tiles, total at wl[96]. ----
__global__ void wl_kernel(const int* __restrict__ cnt, int* __restrict__ wl) {
  const int seg = threadIdx.x;
  if (seg >= 32) return;
  int base = 0;
  for (int s = 0; s < seg; ++s) base += (cnt[s] + 127) >> 7;
  const int nt = (cnt[seg] + 127) >> 7;
  for (int t = 0; t < nt; ++t) wl[base + t] = (seg << 8) | t;
  if (seg == 31) wl[96] = base + nt;
}

// ---------------- bf16 MFMA GEMM: C[m,n] = sum_k A[m,k]*Bt[n,k] + bias[n] ----------------
// 128x128 tile, BK in {64,128}, 4 waves each 64x64 (4x4 of 16x16x32 MFMA), operand-swapped
// epilogue. ROUTED reads its (expert, bseg, tile) from the compacted work list wl.
// GATHER: A rows are gathered through tlist (token indices, hoisted before the K-loop).
// QKV epilogue: n0<512 -> k packed [e][t][512]; else v transposed [e][b][h][64][S].
template <int GELU, int QKV, int ROUTED, int BK, int GATHER>
__global__ __launch_bounds__(256) void gemm_bf16(
    const u16* __restrict__ A, const u16* __restrict__ Bw, const float* __restrict__ bias,
    u16* __restrict__ Cout, u16* __restrict__ vT, int M, int N, int K, long long Astride,
    long long Bstride, const int* __restrict__ wl, const int* __restrict__ tlist) {
  int e;
  long long bm;
  if (ROUTED) {
    const int total = wl[96];
    if ((int)blockIdx.x >= total) return;
    const int item = wl[blockIdx.x];
    const int seg = item >> 8, tile = item & 255;
    e = seg >> 2;
    bm = ((long long)(seg & 3) << 10) + tile * 128;
  } else {
    e = blockIdx.z;
    bm = (long long)blockIdx.x * 128;
  }
  __shared__ __attribute__((aligned(16))) u16 As[128 * BK];
  __shared__ __attribute__((aligned(16))) u16 Bs[128 * BK];
  const int tid = threadIdx.x;
  const int wave = tid >> 6, lane = tid & 63;
  const long long bn = (long long)blockIdx.y * 128;
  const u16* Ag = A + (long long)e * Astride + bm * K;
  const u16* Bg = Bw + ((long long)e * Bstride + bn) * K;
  constexpr int LPR = BK / 8;   // lanes per row in a staging instruction
  constexpr int RPI = 512 / BK; // rows per staging instruction
  constexpr int IPW = BK / 16;  // staging instructions per wave (each of A and B)
  const int lrow = lane / LPR, lpos = lane % LPR;
  const int lm = lane & 15, quad = lane >> 4;
  const int wm = (wave >> 1) * 64, wn = (wave & 1) * 64;
  int tok[IPW];
  if (GATHER) {
    const long long tbase = (long long)e * 4096 + bm;
#pragma unroll
    for (int i = 0; i < IPW; ++i) {
      const int gi = wave * IPW + i;
      tok[i] = tlist[tbase + gi * RPI + lrow];
    }
  }
  f32x4 acc[4][4] = {};
  for (int kk = 0; kk < K; kk += BK) {
    __syncthreads();
#pragma unroll
    for (int i = 0; i < IPW; ++i) {
      const int gi = wave * IPW + i;        // instruction slot 0..BK/4-1
      const int row = gi * RPI + lrow;      // tile row 0..127
      const int sc = lpos ^ (row & 7);      // XOR-swizzled source chunk
      if (GATHER)
        async16(A + (long long)tok[i] * K + kk + sc * 8, &As[gi * 512]);
      else
        async16(Ag + (long long)row * K + kk + sc * 8, &As[gi * 512]);
      async16(Bg + (long long)row * K + kk + sc * 8, &Bs[gi * 512]);
    }
    __syncthreads();
#pragma unroll
    for (int ks = 0; ks < BK / 32; ++ks) {
      bf16x8 af[4], bfr[4];
#pragma unroll
      for (int mi = 0; mi < 4; ++mi) {
        const int row = wm + mi * 16 + lm;
        const int ch = (ks * 4 + quad) ^ (row & 7);
        af[mi] = *(const bf16x8*)(As + row * BK + ch * 8);
      }
#pragma unroll
      for (int nj = 0; nj < 4; ++nj) {
        const int row = wn + nj * 16 + lm;
        const int ch = (ks * 4 + quad) ^ (row & 7);
        bfr[nj] = *(const bf16x8*)(Bs + row * BK + ch * 8);
      }
#pragma unroll
      for (int mi = 0; mi < 4; ++mi)
#pragma unroll
        for (int nj = 0; nj < 4; ++nj)
          acc[mi][nj] = __builtin_amdgcn_mfma_f32_16x16x32_bf16(bfr[nj], af[mi], acc[mi][nj], 0, 0, 0);
    }
  }
  // Epilogue: lane owns row m = bm+wm+mi*16+lm, 4 consecutive cols n0 = bn+wn+nj*16+quad*4
  const float* bs = bias + (long long)e * Bstride;
#pragma unroll
  for (int mi = 0; mi < 4; ++mi) {
    const int m = (int)bm + wm + mi * 16 + lm;
#pragma unroll
    for (int nj = 0; nj < 4; ++nj) {
      const int n0 = (int)bn + wn + nj * 16 + quad * 4;
      const float4 bv = *(const float4*)(bs + n0);
      float v0 = acc[mi][nj][0] + bv.x;
      float v1 = acc[mi][nj][1] + bv.y;
      float v2 = acc[mi][nj][2] + bv.z;
      float v3 = acc[mi][nj][3] + bv.w;
      if (GELU) { v0 = gelu_f(v0); v1 = gelu_f(v1); v2 = gelu_f(v2); v3 = gelu_f(v3); }
      if (QKV) {
        if (n0 < 512) {  // k packed [e][t][512] (branch uniform per block-y)
          uint2 pk; pk.x = pack2bf(v0, v1); pk.y = pack2bf(v2, v3);
          *(uint2*)(Cout + ((long long)e * Mc + m) * 512 + n0) = pk;
        } else {  // v stored transposed [e][b][h][64][S]; 4 consecutive d -> 4 rows
          const int hh = (n0 - 512) >> 6, dd = (n0 - 512) & 63;
          const int bb = m >> 10, ss = m & 1023;
          u16* vp = vT + ((((long long)e * Bc + bb) * Hc + hh) * 64 + dd) * Sc + ss;
          vp[0] = f2bf(v0); vp[Sc] = f2bf(v1); vp[2 * Sc] = f2bf(v2); vp[3 * Sc] = f2bf(v3);
        }
      } else {
        uint2 pk; pk.x = pack2bf(v0, v1); pk.y = pack2bf(v2, v3);
        *(uint2*)(Cout + ((long long)e * M + m) * N + n0) = pk;
      }
    }
  }
}

// -------- flash attention: ONE block per (128-row q-pair, head). 1D grid with head in --------
// the LOW 3 bits of blockIdx.x: linear-id mod 8 = head -> all blocks of head h land on
// XCD h (round-robin dispatch), so K/V chunk re-reads across q-tiles of a segment hit
// that XCD's L2 instead of being duplicated across 8 XCDs (prev FETCH 164 MB, 37% HBM).
// 128 q rows per block also halves staging rounds per K/V byte.
__global__ __launch_bounds__(256, 4) void attn_tile(const u16* __restrict__ qb,
                                                    const u16* __restrict__ kb,
                                                    const u16* __restrict__ vT,
                                                    u16* __restrict__ ctx,
                                                    const int* __restrict__ wl) {
  const int idx = blockIdx.x >> 3, h = blockIdx.x & 7;
  if (idx >= wl[96]) return;
  const int item = wl[idx];
  const int seg = item >> 8, tile = item & 255;
  const int e = seg >> 2, b = seg & 3;
  __shared__ __attribute__((aligned(16))) u16 Ks[64 * 64];     // [key][d] swizzled
  __shared__ __attribute__((aligned(16))) u16 Vs[64 * 64];     // [d][key] swizzled
  __shared__ __attribute__((aligned(16))) u16 Pl[4][16 * 72];  // per-wave P[q][key], stride 72
  const int tid = threadIdx.x, wave = tid >> 6, lane = tid & 63;
  const int lm = lane & 15, quad = lane >> 4;
  const u16* kbase = kb + ((long long)e * Mc + b * Sc) * 512;
  const u16* vbase = vT + ((((long long)e * Bc + b) * Hc + h) * 64) * Sc;
  const int lr = lane >> 3, lc = (lane & 7) ^ lr;
  u16* P = &Pl[wave][0];
  unsigned* P32 = (unsigned*)P;
  const int pwbase = lm * 36 + quad * 2;  // dword index of this lane's P writes

  // q fragments for this lane's rows in both 64-row sub-tiles (compact layout)
  const long long pidx0 = (long long)seg * 1024 + tile * 128 + wave * 16 + lm;
  bf16x8 aq[2][2];
#pragma unroll
  for (int t = 0; t < 2; ++t)
#pragma unroll
    for (int ks = 0; ks < 2; ++ks)
      aq[t][ks] = *(const bf16x8*)(qb + (pidx0 + t * 64) * 512 + h * 64 + ks * 32 + quad * 8);
  f32x4 O[2][4] = {};
  float lsum[2] = {0.f, 0.f};

  for (int n0 = 0; n0 < Sc; n0 += 64) {
    __syncthreads();
#pragma unroll
    for (int i = 0; i < 2; ++i) {
      const int rg = wave * 2 + i;  // 0..7
      const int row = rg * 8 + lr;  // 0..63
      async16(kbase + (long long)(n0 + row) * 512 + h * 64 + lc * 8, &Ks[rg * 512]);
      async16(vbase + (long long)row * Sc + n0 + lc * 8, &Vs[rg * 512]);
    }
    __syncthreads();
    // hoist K fragments (shared by both q sub-tiles)
    bf16x8 kf[4][2];
#pragma unroll
    for (int kj = 0; kj < 4; ++kj) {
      const int row = kj * 16 + lm;
      kf[kj][0] = *(const bf16x8*)(Ks + row * 64 + ((quad) ^ (row & 7)) * 8);
      kf[kj][1] = *(const bf16x8*)(Ks + row * 64 + ((4 + quad) ^ (row & 7)) * 8);
    }
    bf16x8 ap[2][2];
#pragma unroll
    for (int t = 0; t < 2; ++t) {
      // S^T = K @ Q^T : C-layout row = key = kj*16 + quad*4 + r, col = q = lm
      f32x4 sT[4];
#pragma unroll
      for (int kj = 0; kj < 4; ++kj) {
        f32x4 c = {};
        c = __builtin_amdgcn_mfma_f32_16x16x32_bf16(kf[kj][0], aq[t][0], c, 0, 0, 0);
        c = __builtin_amdgcn_mfma_f32_16x16x32_bf16(kf[kj][1], aq[t][1], c, 0, 0, 0);
        sT[kj] = c;
      }
      // p = exp(s/8) (scores bounded -> no running-max rescale); local denom
#pragma unroll
      for (int kj = 0; kj < 4; ++kj) {
        const float p0 = __expf(sT[kj][0] * 0.125f);
        const float p1 = __expf(sT[kj][1] * 0.125f);
        const float p2 = __expf(sT[kj][2] * 0.125f);
        const float p3 = __expf(sT[kj][3] * 0.125f);
        lsum[t] += (p0 + p1) + (p2 + p3);
        P32[pwbase + kj * 8 + 0] = pack2bf(p0, p1);
        P32[pwbase + kj * 8 + 1] = pack2bf(p2, p3);
      }
      asm volatile("s_waitcnt lgkmcnt(0)" ::: "memory");
      ap[t][0] = *(const bf16x8*)(P + lm * 72 + quad * 8);
      ap[t][1] = *(const bf16x8*)(P + lm * 72 + 32 + quad * 8);
    }
    // PV with hoisted V fragments: O^T[d][q] += V^T[d][key] * P[q][key]
#pragma unroll
    for (int d4 = 0; d4 < 4; ++d4) {
      const int row = d4 * 16 + lm;
      const bf16x8 v0 = *(const bf16x8*)(Vs + row * 64 + ((quad) ^ (row & 7)) * 8);
      const bf16x8 v1 = *(const bf16x8*)(Vs + row * 64 + ((4 + quad) ^ (row & 7)) * 8);
#pragma unroll
      for (int t = 0; t < 2; ++t) {
        O[t][d4] = __builtin_amdgcn_mfma_f32_16x16x32_bf16(v0, ap[t][0], O[t][d4], 0, 0, 0);
        O[t][d4] = __builtin_amdgcn_mfma_f32_16x16x32_bf16(v1, ap[t][1], O[t][d4], 0, 0, 0);
      }
    }
  }
#pragma unroll
  for (int t = 0; t < 2; ++t) {
    float ls = lsum[t];
    ls += __shfl_xor(ls, 16);
    ls += __shfl_xor(ls, 32);
    const float inv = 1.0f / ls;  // per-lane correct for q = lm
#pragma unroll
    for (int d4 = 0; d4 < 4; ++d4) {
      uint2 pk;
      pk.x = pack2bf(O[t][d4][0] * inv, O[t][d4][1] * inv);
      pk.y = pack2bf(O[t][d4][2] * inv, O[t][d4][3] * inv);
      *(uint2*)(ctx + (pidx0 + t * 64) * 512 + h * 64 + d4 * 16 + quad * 4) = pk;
    }
  }
}

// ---------------- LN1 (routed): x1[p] = LN(x[tlist[p]] + ctxp[p]; g1,be1) -> bf16 ----------------
__global__ __launch_bounds__(256) void ln1_kernel(const float* __restrict__ x,
                                                  const u16* __restrict__ ctxp,
                                                  const float* __restrict__ g1,
                                                  const float* __restrict__ be1,
                                                  u16* __restrict__ x1,
                                                  const int* __restrict__ cnt,
                                                  const int* __restrict__ tlist) {
  const int i = blockIdx.x, b = blockIdx.y, e = blockIdx.z;
  const int seg = (e << 2) + b;
  const int ce = (cnt[seg] + 127) & ~127;
  if (i >= ce) return;  // compute all padded rows so downstream GEMM reads defined data
  const long long p = seg * 1024 + i;
  const int t = tlist[p];
  const int tid = threadIdx.x;
  const int wave = tid >> 6, lane = tid & 63;
  __shared__ float sred[4], qred[4];
  const float v0 = x[(long long)t * 512 + tid] + bf2f(ctxp[p * 512 + tid]);
  const float v1 = x[(long long)t * 512 + tid + 256] + bf2f(ctxp[p * 512 + tid + 256]);
  float s = v0 + v1, q = v0 * v0 + v1 * v1;
#pragma unroll
  for (int off = 32; off; off >>= 1) { s += __shfl_xor(s, off); q += __shfl_xor(q, off); }
  if (lane == 0) { sred[wave] = s; qred[wave] = q; }
  __syncthreads();
  s = sred[0] + sred[1] + sred[2] + sred[3];
  q = qred[0] + qred[1] + qred[2] + qred[3];
  const float mean = s * (1.0f / 512.0f);
  const float var = q * (1.0f / 512.0f) - mean * mean;
  const float rstd = rsqrtf(var + 1e-5f);
  x1[p * 512 + tid] = f2bf((v0 - mean) * rstd * g1[e * 512 + tid] + be1[e * 512 + tid]);
  x1[p * 512 + tid + 256] =
      f2bf((v1 - mean) * rstd * g1[e * 512 + tid + 256] + be1[e * 512 + tid + 256]);
}

// ---------------- LN2 + gate-weighted combine: out[t] = sum_e w[t,e]*LN(x1[p]+h2[p]) ----------------
__global__ __launch_bounds__(256) void ln2_kernel(const u16* __restrict__ x1,
                                                  const u16* __restrict__ h2,
                                                  const float* __restrict__ g2,
                                                  const float* __restrict__ be2,
                                                  const float* __restrict__ gated,
                                                  const int* __restrict__ pos,
                                                  float* __restrict__ out) {
  const int t = blockIdx.x, tid = threadIdx.x;
  const int b = t >> 10;
  const int wave = tid >> 6, lane = tid & 63;
  __shared__ float sred[4], qred[4];
  float o0 = 0.f, o1 = 0.f;
  for (int e = 0; e < 8; ++e) {
    const float wgt = gated[t * 8 + e];
    if (wgt != 0.f) {  // block-uniform branch (depends on t only)
      const long long p = ((e << 2) + b) * 1024 + pos[e * 4096 + t];
      const float v0 = bf2f(x1[p * 512 + tid]) + bf2f(h2[p * 512 + tid]);
      const float v1 = bf2f(x1[p * 512 + tid + 256]) + bf2f(h2[p * 512 + tid + 256]);
      float s = v0 + v1, q = v0 * v0 + v1 * v1;
#pragma unroll
      for (int off = 32; off; off >>= 1) { s += __shfl_xor(s, off); q += __shfl_xor(q, off); }
      if (lane == 0) { sred[wave] = s; qred[wave] = q; }
      __syncthreads();
      s = sred[0] + sred[1] + sred[2] + sred[3];
      q = qred[0] + qred[1] + qred[2] + qred[3];
      __syncthreads();
      const float mean = s * (1.0f / 512.0f);
      const float var = q * (1.0f / 512.0f) - mean * mean;
      const float rstd = rsqrtf(var + 1e-5f);
      o0 += wgt * ((v0 - mean) * rstd * g2[e * 512 + tid] + be2[e * 512 + tid]);
      o1 += wgt * ((v1 - mean) * rstd * g2[e * 512 + tid + 256] + be2[e * 512 + tid + 256]);
    }
  }
  out[(long long)t * 512 + tid] = o0;
  out[(long long)t * 512 + tid + 256] = o1;
}

// ---------------- launch ----------------
extern "C" void kernel_launch(void* const* d_in, const int* in_sizes, int n_in, void* d_out,
                              int out_size, void* d_ws, size_t ws_size, hipStream_t stream) {
  const float* x    = (const float*)d_in[0];
  const float* gWk  = (const float*)d_in[1];
  const float* gbk  = (const float*)d_in[2];
  const float* eq   = (const float*)d_in[3];
  const float* Wqkv = (const float*)d_in[4];
  const float* bqkv = (const float*)d_in[5];
  const float* Wo   = (const float*)d_in[6];
  const float* bo   = (const float*)d_in[7];
  const float* g1   = (const float*)d_in[8];
  const float* be1  = (const float*)d_in[9];
  const float* W1   = (const float*)d_in[10];
  const float* bf1  = (const float*)d_in[11];
  const float* W2   = (const float*)d_in[12];
  const float* bf2  = (const float*)d_in[13];
  const float* g2   = (const float*)d_in[14];
  const float* be2  = (const float*)d_in[15];
  float* out = (float*)d_out;

  char* wsp = (char*)d_ws;
  size_t off = 0;
  auto take = [&](size_t bytes) -> void* {
    void* p = wsp + off;
    off += (bytes + 255) & ~(size_t)255;
    return p;
  };
  u16* xb    = (u16*)take((size_t)Mc * 512 * 2);
  u16* Wqkvb = (u16*)take((size_t)Ec * 1536 * 512 * 2);
  u16* Wob   = (u16*)take((size_t)Ec * 512 * 512 * 2);
  u16* W1b   = (u16*)take((size_t)Ec * 2048 * 512 * 2);
  u16* W2b   = (u16*)take((size_t)Ec * 512 * 2048 * 2);
  float* weq   = (float*)take(8 * 512 * 4);
  float* beqb  = (float*)take(8 * 4);
  float* gated = (float*)take((size_t)Mc * 8 * 4);
  int* cnt   = (int*)take(32 * 4);
  int* tlist = (int*)take(32 * 1024 * 4);
  int* pos   = (int*)take((size_t)Ec * Mc * 4);
  int* wl    = (int*)take(512 * 4);
  char* big = (char*)take(134217728);
  u16* qb   = (u16*)big;                  // compact q [32768][512], dead after attn
  u16* kb   = (u16*)(big + 33554432);     // k [E][M][512], dead after attn
  u16* vTb  = (u16*)(big + 67108864);     // [E][B][H][64][S], dead after attn
  u16* ctxp = (u16*)(big + 100663296);    // compact [32768][512], dead after ln1
  u16* hb   = (u16*)big;                  // compact [32768][2048], written after ln1
  u16* ctxb = (u16*)take(33554432);       // compact attn out, dead after Wo GEMM
  u16* h2b  = ctxb;                       // compact W2 out, written after W1
  u16* x1b  = (u16*)take(33554432);       // compact [32768][512]
  (void)in_sizes; (void)n_in; (void)out_size; (void)ws_size;

  // fp32 -> bf16 converts (single fused launch)
  cvt5_kernel<<<dim3(26624), dim3(256), 0, stream>>>(x, xb, Wqkv, Wqkvb, Wo, Wob, W1, W1b, W2, W2b);
  // gating (fp32 path; keys GEMM folded into weq precompute)
  hipMemsetAsync(cnt, 0, 32 * 4, stream);
  weq_kernel<<<dim3(8, 8), dim3(256), 0, stream>>>(gWk, eq, weq);
  beq_kernel<<<dim3(1), dim3(256), 0, stream>>>(gbk, eq, beqb);
  gate_kernel<<<dim3(1024), dim3(256), 0, stream>>>(x, weq, beqb, gated, cnt, tlist, pos);
  pad_kernel<<<dim3(32), dim3(128), 0, stream>>>(cnt, tlist);
  wl_kernel<<<dim3(1), dim3(64), 0, stream>>>(cnt, wl);
  // kv dense (k,v needed at all tokens; q only at routed rows) — N=1024, BK=64
  gemm_bf16<0, 1, 0, 64, 0><<<dim3(32, 8, 8), dim3(256), 0, stream>>>(
      xb, Wqkvb + 512 * 512, bqkv + 512, kb, vTb, Mc, 1024, 512, 0LL, 1536LL, wl, nullptr);
  // q routed (A rows gathered through tlist), compact output
  gemm_bf16<0, 0, 1, 128, 1><<<dim3(96, 4), dim3(256), 0, stream>>>(
      xb, Wqkvb, bqkv, qb, nullptr, Mc, 512, 512, 0LL, 1536LL, wl, tlist);
  // routed expert pipeline — worklist-compacted grids; attn grid is 1D with head in the
  // low 3 bits (head -> XCD pinning for K/V L2 reuse)
  attn_tile<<<dim3(96 * 8), dim3(256), 0, stream>>>(qb, kb, vTb, ctxb, wl);
  gemm_bf16<0, 0, 1, 128, 0><<<dim3(96, 4), dim3(256), 0, stream>>>(
      ctxb, Wob, bo, ctxp, nullptr, Mc, 512, 512, (long long)Mc * 512, 512LL, wl, nullptr);
  ln1_kernel<<<dim3(1024, 4, 8), dim3(256), 0, stream>>>(x, ctxp, g1, be1, x1b, cnt, tlist);
  gemm_bf16<1, 0, 1, 128, 0><<<dim3(96, 16), dim3(256), 0, stream>>>(
      x1b, W1b, bf1, hb, nullptr, Mc, 2048, 512, (long long)Mc * 512, 2048LL, wl, nullptr);
  gemm_bf16<1, 0, 1, 128, 0><<<dim3(96, 4), dim3(256), 0, stream>>>(
      hb, W2b, bf2, h2b, nullptr, Mc, 512, 2048, (long long)Mc * 2048, 512LL, wl, nullptr);
  ln2_kernel<<<dim3(4096), dim3(256), 0, stream>>>(x1b, h2b, g2, be2, gated, pos, out);
}